// Round 8
// baseline (4486.821 us; speedup 1.0000x reference)
//
#include <hip/hip_runtime.h>
#include <math.h>

// FNO2d: B=8, CIN=2, COUT=1, W0=64, modes 16x16, NL=4, H=W=256
// h stored channels-last: [B][H][W][64]
// Y (F1 out): [B][H(x)][16ky][64c][2]   (shares buffer with A)
// Xf (F2 out): [B][64c][256m][2], m = kx*16+ky
// A (I1 out): [B][H(x)][16ky][64o][2] -- FULLY pre-scaled for k_pw:
//   ky=0: x(1/256) [I1 1/16 * I2 1/16], ky>=1: x(1/128) [extra irfft factor 2]
//   (R7 bug: 0.0625/0.125 dropped I2's 1/16 -> spectral branch 16x too big,
//    2.2% end-to-end error. All scale factors must be exact powers of 2.)
//
// HARD-WON RULE (R2/R3/R5): NEVER use the min-waves arg of __launch_bounds__
// on kernels with per-thread accumulator arrays -- the backend spills to meet
// the occupancy target (VGPR tier 64/32) and FETCH/WRITE balloon to GBs.
// R4=R6 lesson: k_pw with o-tiled waves is latency-bound on s_load weight
// streaming (lgkmcnt shared with ds_read), not on h access.

#define NLAYER 4

// ws offsets in floats
#define OFF_H    0L
#define SZ_H     33554432L            // 8*256*256*64
#define OFF_YA   33554432L
#define SZ_YA    4194304L             // 8*256*16*64*2
#define OFF_XF   37748736L
#define SZ_XF    262144L              // 8*64*256*2
#define OFF_TAB  38010880L
#define OFF_PWT  38011136L            // 4*64*64
#define OFF_O1T  38027520L            // 64*32
#define WS_FLOATS 38029568L

__global__ void k_init(float* __restrict__ ws, const float* __restrict__ pw_w,
                       const float* __restrict__ o1_w) {
  float* costab = ws + OFF_TAB;
  float* pwT = ws + OFF_PWT;
  float* o1T = ws + OFF_O1T;
  int t = blockIdx.x * blockDim.x + threadIdx.x;
  int stride = gridDim.x * blockDim.x;
  for (int m = t; m < 256; m += stride)
    costab[m] = (float)cos((double)m * (3.14159265358979323846 / 128.0));
  for (int idx = t; idx < NLAYER * 64 * 64; idx += stride) {
    int l = idx >> 12; int r = idx & 4095; int i = r >> 6; int o = r & 63;
    pwT[idx] = pw_w[((l * 64 + o) << 6) + i];   // pwT[l][i][o] = pw_w[l][o][i]
  }
  for (int idx = t; idx < 64 * 32; idx += stride) {
    int i = idx >> 5; int o = idx & 31;
    o1T[idx] = o1_w[(o << 6) + i];              // o1T[i][o] = o1_w[o][i]
  }
}

// input 1x1 conv: x [B][2][H][W] -> h [B][H][W][64]. 4 outputs/thread.
__global__ void __launch_bounds__(256) k_in(const float* __restrict__ x,
                                            const float* __restrict__ in_w,
                                            const float* __restrict__ in_b,
                                            float* __restrict__ h) {
  long tid = (long)blockIdx.x * 256 + threadIdx.x;   // [0, 8*65536*16)
  int o0 = (int)(tid & 15) << 2;
  long p = tid >> 4;                                  // pixel index
  long b = p >> 16; long xy = p & 65535;
  float x0 = x[b * 131072 + xy];
  float x1 = x[b * 131072 + 65536 + xy];
  float4 r;
  r.x = in_b[o0]     + in_w[o0 * 2]     * x0 + in_w[o0 * 2 + 1] * x1;
  r.y = in_b[o0 + 1] + in_w[o0 * 2 + 2] * x0 + in_w[o0 * 2 + 3] * x1;
  r.z = in_b[o0 + 2] + in_w[o0 * 2 + 4] * x0 + in_w[o0 * 2 + 5] * x1;
  r.w = in_b[o0 + 3] + in_w[o0 * 2 + 6] * x0 + in_w[o0 * 2 + 7] * x1;
  *(float4*)(h + (p << 6) + o0) = r;
}

// F1: partial DFT along y. block = (b,x) [2048], thread: cg=t&15 (c0=4*cg), ky=t>>4
__global__ void __launch_bounds__(256) k_f1(const float* __restrict__ h,
                                            const float* __restrict__ costab,
                                            float* __restrict__ Y) {
  __shared__ float T[256];
  int t = threadIdx.x;
  T[t] = costab[t];
  __syncthreads();
  int cg = t & 15, ky = t >> 4;
  int c0 = cg << 2;
  const float* hrow = h + ((long)blockIdx.x << 14) + c0;
  float r0 = 0, r1 = 0, r2 = 0, r3 = 0, i0 = 0, i1 = 0, i2 = 0, i3 = 0;
  int m = 0;
  for (int y = 0; y < 256; ++y) {
    float4 v = *(const float4*)(hrow + (y << 6));
    float cv = T[m], sv = T[(m + 192) & 255];
    r0 += v.x * cv; i0 -= v.x * sv;
    r1 += v.y * cv; i1 -= v.y * sv;
    r2 += v.z * cv; i2 -= v.z * sv;
    r3 += v.w * cv; i3 -= v.w * sv;
    m = (m + ky) & 255;
  }
  const float s = 0.0625f;
  float* out = Y + ((long)blockIdx.x * 16 + ky) * 128 + c0 * 2;
  *(float4*)out = make_float4(r0 * s, i0 * s, r1 * s, i1 * s);
  *(float4*)(out + 4) = make_float4(r2 * s, i2 * s, r3 * s, i3 * s);
}

// F2: partial DFT along x. block = b*16+ky [128], thread: c=t&63, kxg=t>>6 (4 kx each)
__global__ void __launch_bounds__(256) k_f2(const float* __restrict__ Y,
                                            const float* __restrict__ costab,
                                            float* __restrict__ Xf) {
  __shared__ float T[256];
  int t = threadIdx.x;
  T[t] = costab[t];
  __syncthreads();
  int b = blockIdx.x >> 4, ky = blockIdx.x & 15;
  int c = t & 63, kxg = t >> 6;
  float accr[4] = {0, 0, 0, 0}, acci[4] = {0, 0, 0, 0};
  const float* ybase = Y + ((long)b * 4096 + ky) * 128 + c * 2;
  int mj[4];
  #pragma unroll
  for (int j = 0; j < 4; ++j) mj[j] = 0;
  for (int x = 0; x < 256; ++x) {
    float2 v = *(const float2*)(ybase + (long)x * 2048);
    #pragma unroll
    for (int j = 0; j < 4; ++j) {
      int kx = kxg * 4 + j;
      float cv = T[mj[j]], sv = T[(mj[j] + 192) & 255];
      accr[j] += v.x * cv + v.y * sv;   // (yr+i yi)(c - i s)
      acci[j] += v.y * cv - v.x * sv;
      mj[j] = (mj[j] + kx) & 255;
    }
  }
  const float s = 0.0625f;
  #pragma unroll
  for (int j = 0; j < 4; ++j) {
    int kx = kxg * 4 + j;
    float* o = Xf + ((long)b * 64 + c) * 512 + (kx * 16 + ky) * 2;
    o[0] = accr[j] * s;
    o[1] = acci[j] * s;
  }
}

// mode GEMM + I1. block = b*64+o [512]. phase1: thread=mode m; phase2: thread=x.
// A output FULLY pre-scaled for k_pw: ky=0 -> 1/256, ky>=1 -> 1/128
// (= I1 1/16 * I2 1/16 * [2 for positive-freq bins]).
__global__ void __launch_bounds__(256) k_spec(const float* __restrict__ Xf,
                                              const float* __restrict__ wr,
                                              const float* __restrict__ wi,
                                              const float* __restrict__ costab,
                                              float* __restrict__ A) {
  __shared__ float T[256];
  __shared__ float Gr[256], Gi[256];
  int t = threadIdx.x;
  T[t] = costab[t];
  int b = blockIdx.x >> 6, o = blockIdx.x & 63;
  {
    int m = t;
    float gr = 0, gi = 0;
    const float* xb = Xf + (long)b * 32768 + m * 2;
    const float* wrb = wr + (long)o * 256 + m;    // [i][o][m]
    const float* wib = wi + (long)o * 256 + m;
    for (int i = 0; i < 64; ++i) {
      float xr = xb[(long)i * 512], xi = xb[(long)i * 512 + 1];
      float wrv = wrb[(long)i * 16384], wiv = wib[(long)i * 16384];
      gr += xr * wrv - xi * wiv;
      gi += xr * wiv + xi * wrv;
    }
    Gr[m] = gr; Gi[m] = gi;
  }
  __syncthreads();
  int x = t;
  float ar[16], ai[16];
  #pragma unroll
  for (int ky = 0; ky < 16; ++ky) { ar[ky] = 0.0f; ai[ky] = 0.0f; }
  for (int kx = 0; kx < 16; ++kx) {
    int mm = (kx * x) & 255;
    float cv = T[mm], sv = T[(mm + 192) & 255];
    #pragma unroll
    for (int ky = 0; ky < 16; ++ky) {
      float gr = Gr[kx * 16 + ky], gi = Gi[kx * 16 + ky];
      ar[ky] += gr * cv - gi * sv;     // (gr+i gi)(c + i s)
      ai[ky] += gr * sv + gi * cv;
    }
  }
  float* ab = A + ((long)b * 256 + x) * 2048 + o * 2;
  #pragma unroll
  for (int ky = 0; ky < 16; ++ky) {
    float sc = (ky == 0) ? 0.00390625f : 0.0078125f;   // 1/256, 1/128 (exact)
    ab[ky * 128] = ar[ky] * sc;
    ab[ky * 128 + 1] = ai[ky] * sc;
  }
}

// I2 + pointwise conv + GELU, in place on h.
// v8 = v7 structure, corrected A pre-scale (see k_spec).
// lane = o (64 lanes = 64 out-channels), each thread computes 8 y's.
// Weights live in lane-private VGPRs (wv[64], loaded once, coalesced) ->
// GEMM inner loop is pure v_fmac VGPR x VGPR, zero weight loads, 8
// independent acc chains. h tile (32y x 64c, 8KB LDS) read via wave-uniform
// broadcast ds_read_b128. A coefficients per-lane coalesced float2 (dead
// before GEMM so Ar/Ai and wv don't overlap in the live set). cos/sin for
// I2 are wave-uniform -> scalar path from global costab.
__global__ void __launch_bounds__(256) k_pw(float* __restrict__ h,
                                            const float* __restrict__ A,
                                            const float* __restrict__ pwT,
                                            const float* __restrict__ pw_b,
                                            const float* __restrict__ costab) {
  __shared__ float S[32 * 64];
  int t = threadIdx.x;
  long row = blockIdx.x >> 3;                  // (b,x) in [0,2048)
  int yo = blockIdx.x & 7;                     // 32-y sub-tile
  const float* hbase = h + (row << 14) + ((long)yo << 11);
  #pragma unroll
  for (int k = 0; k < 2; ++k) {
    int i4 = t + (k << 8);                     // [0,512) float4s
    *(float4*)(&S[i4 << 2]) = *(const float4*)(hbase + (i4 << 2));
  }
  int lane = t & 63;
  int wid = __builtin_amdgcn_readfirstlane(t >> 6);   // 0..3
  // per-lane A row (o = lane): coalesced float2 loads
  const float* Ab = A + row * 2048;
  float Ar[16], Ai[16];
  #pragma unroll
  for (int ky = 0; ky < 16; ++ky) {
    float2 v = *(const float2*)(Ab + (ky << 7) + (lane << 1));
    Ar[ky] = v.x; Ai[ky] = v.y;
  }
  float bias = pw_b[lane];
  int y0 = (yo << 5) + (wid << 3);
  float acc[8];
  #pragma unroll
  for (int i = 0; i < 8; ++i) {
    int y = y0 + i;                            // wave-uniform
    float a = Ar[0] + bias;                    // ky=0: Re only (irfft DC)
    #pragma unroll
    for (int ky = 1; ky < 16; ++ky) {
      int mm = (ky * y) & 255;                 // uniform -> scalar path
      float cv = costab[mm];
      float sv = costab[(mm + 192) & 255];
      a += Ar[ky] * cv - Ai[ky] * sv;          // scales pre-baked in A
    }
    acc[i] = a;
  }
  // weights per-lane (after I2 so Ar/Ai are dead): wv[c] = pwT[c][lane]
  float wv[64];
  #pragma unroll
  for (int c = 0; c < 64; ++c) wv[c] = pwT[(c << 6) + lane];
  __syncthreads();                             // S staged; h reads done
  int ly0 = wid << 3;
  #pragma unroll
  for (int c = 0; c < 64; c += 4) {
    float4 hv[8];
    #pragma unroll
    for (int i = 0; i < 8; ++i)
      hv[i] = *(const float4*)(&S[((ly0 + i) << 6) + c]);   // broadcast read
    #pragma unroll
    for (int i = 0; i < 8; ++i)
      acc[i] += hv[i].x * wv[c] + hv[i].y * wv[c + 1] +
                hv[i].z * wv[c + 2] + hv[i].w * wv[c + 3];
  }
  float* ob = h + (row << 14) + ((long)y0 << 6) + lane;
  #pragma unroll
  for (int i = 0; i < 8; ++i) {
    float v = acc[i];
    v = 0.5f * v * (1.0f + erff(v * 0.70710678118654752f));
    ob[(long)i << 6] = v;                      // coalesced across lanes
  }
}

// output: gelu(o1) then o2. thread = pixel. h streamed (no hv[64] preload).
__global__ void __launch_bounds__(256) k_out(const float* __restrict__ h,
                                             const float* __restrict__ o1T,
                                             const float* __restrict__ o1_b,
                                             const float* __restrict__ o2_w,
                                             const float* __restrict__ o2_b,
                                             float* __restrict__ out) {
  long p = (long)blockIdx.x * 256 + threadIdx.x;
  const float* hp = h + (p << 6);
  float t32[32];
  #pragma unroll
  for (int o = 0; o < 32; ++o) t32[o] = o1_b[o];
  #pragma unroll
  for (int j = 0; j < 16; ++j) {
    float4 hv = *(const float4*)(hp + j * 4);
    #pragma unroll
    for (int k = 0; k < 4; ++k) {
      float hvv = (k == 0) ? hv.x : (k == 1) ? hv.y : (k == 2) ? hv.z : hv.w;
      const float* w = o1T + ((j * 4 + k) << 5);
      #pragma unroll
      for (int o = 0; o < 32; ++o) t32[o] += hvv * w[o];
    }
  }
  float r = o2_b[0];
  #pragma unroll
  for (int o = 0; o < 32; ++o) {
    float v = t32[o];
    v = 0.5f * v * (1.0f + erff(v * 0.70710678118654752f));
    r += o2_w[o] * v;
  }
  out[p] = r;
}

extern "C" void kernel_launch(void* const* d_in, const int* in_sizes, int n_in,
                              void* d_out, int out_size, void* d_ws, size_t ws_size,
                              hipStream_t stream) {
  const float* x       = (const float*)d_in[0];
  const float* in_w    = (const float*)d_in[1];
  const float* in_b    = (const float*)d_in[2];
  const float* spec_wr = (const float*)d_in[3];
  const float* spec_wi = (const float*)d_in[4];
  const float* pw_w    = (const float*)d_in[5];
  const float* pw_b    = (const float*)d_in[6];
  const float* o1_w    = (const float*)d_in[7];
  const float* o1_b    = (const float*)d_in[8];
  const float* o2_w    = (const float*)d_in[9];
  const float* o2_b    = (const float*)d_in[10];
  float* ws = (float*)d_ws;
  float* h      = ws + OFF_H;
  float* YA     = ws + OFF_YA;
  float* Xf     = ws + OFF_XF;
  float* costab = ws + OFF_TAB;
  float* pwT    = ws + OFF_PWT;
  float* o1T    = ws + OFF_O1T;
  float* out = (float*)d_out;

  k_init<<<73, 256, 0, stream>>>(ws, pw_w, o1_w);
  k_in<<<32768, 256, 0, stream>>>(x, in_w, in_b, h);
  for (int l = 0; l < NLAYER; ++l) {
    k_f1<<<2048, 256, 0, stream>>>(h, costab, YA);
    k_f2<<<128, 256, 0, stream>>>(YA, costab, Xf);
    k_spec<<<512, 256, 0, stream>>>(Xf, spec_wr + (long)l * 1048576,
                                    spec_wi + (long)l * 1048576, costab, YA);
    k_pw<<<16384, 256, 0, stream>>>(h, YA, pwT + l * 4096, pw_b + l * 64, costab);
  }
  k_out<<<2048, 256, 0, stream>>>(h, o1T, o1_b, o2_w, o2_b, out);
}

// Round 9
// 1406.715 us; speedup vs baseline: 3.1896x; 3.1896x over previous
//
#include <hip/hip_runtime.h>
#include <math.h>

// FNO2d: B=8, CIN=2, COUT=1, W0=64, modes 16x16, NL=4, H=W=256
// h stored channels-last fp32: [B][H][W][64]
// Y  (F1 out, fp32): [B][H(x)][16ky][64c][2]
// Xf (F2 out, fp32): [B][64c][256m][2], m = kx*16+ky
// A2 (spec out, bf16): [B*256 rows][64o][32k']  k'<16: Ar*sc, k'>=16: -Ai*sc
//     sc = 1/256 (ky=0) else 1/128. OVERLAYS Y (Y dead after k_f2).
// Trig (bf16, const): [256y][32k']  k'<16: cos(2pi k'y/256), else sin(2pi(k'-16)y/256)
// k_pw = single bf16 MFMA GEMM: [H | Trig] @ [pw_w^T ; A2] + bias -> gelu.
//
// HARD-WON RULES:
//  - (R2/R3/R5) NEVER use min-waves arg of __launch_bounds__ with per-thread
//    accumulator arrays: backend spills to hit the VGPR tier, GBs of traffic.
//  - (R4-R8) fp32-VALU k_pw is structurally latency/register-bound at ~750us;
//    MFMA path avoids staging weights through regs/SGPRs entirely.
//  - Harness compares output in bf16; threshold = 2% of max = ~4.5 bf16 ulps.

#define NLAYER 4

// ws offsets in floats
#define OFF_H    0L
#define OFF_YA   33554432L            // Y fp32 (4194304 fl) / A2 bf16 overlay
#define OFF_XF   37748736L            // 262144 fl
#define OFF_TAB  38010880L            // 256 fl
#define OFF_O1T  38011136L            // 2048 fl
#define OFF_TRIG 38013184L            // 8192 ush = 4096 fl
#define OFF_WT   38017280L            // 16384 ush = 8192 fl
#define WS_FLOATS 38025472L

typedef __attribute__((ext_vector_type(8))) short short8;
typedef __attribute__((ext_vector_type(4))) float f32x4;

__device__ __forceinline__ unsigned short f2bf(float f) {
  unsigned int u = __float_as_uint(f);
  u += 0x7FFF + ((u >> 16) & 1);          // round-to-nearest-even
  return (unsigned short)(u >> 16);
}

__global__ void k_init(float* __restrict__ ws, const float* __restrict__ pw_w,
                       const float* __restrict__ o1_w) {
  float* costab = ws + OFF_TAB;
  float* o1T = ws + OFF_O1T;
  unsigned short* trig = (unsigned short*)(ws + OFF_TRIG);
  unsigned short* wt = (unsigned short*)(ws + OFF_WT);
  int t = blockIdx.x * blockDim.x + threadIdx.x;
  int stride = gridDim.x * blockDim.x;
  for (int m = t; m < 256; m += stride)
    costab[m] = (float)cos((double)m * (3.14159265358979323846 / 128.0));
  for (int idx = t; idx < 64 * 32; idx += stride) {
    int i = idx >> 5; int o = idx & 31;
    o1T[idx] = o1_w[(o << 6) + i];              // o1T[i][o] = o1_w[o][i]
  }
  for (int idx = t; idx < 256 * 32; idx += stride) {
    int y = idx >> 5, k = idx & 31;
    int mm = ((k & 15) * y) & 255;
    double ang = (double)mm * (3.14159265358979323846 / 128.0);
    double v = (k < 16) ? cos(ang) : sin(ang);
    trig[idx] = f2bf((float)v);
  }
  for (int idx = t; idx < NLAYER * 64 * 64; idx += stride)
    wt[idx] = f2bf(pw_w[idx]);                  // same [l][o][c] layout
}

// input 1x1 conv: x [B][2][H][W] -> h [B][H][W][64]. 4 outputs/thread.
__global__ void __launch_bounds__(256) k_in(const float* __restrict__ x,
                                            const float* __restrict__ in_w,
                                            const float* __restrict__ in_b,
                                            float* __restrict__ h) {
  long tid = (long)blockIdx.x * 256 + threadIdx.x;   // [0, 8*65536*16)
  int o0 = (int)(tid & 15) << 2;
  long p = tid >> 4;                                  // pixel index
  long b = p >> 16; long xy = p & 65535;
  float x0 = x[b * 131072 + xy];
  float x1 = x[b * 131072 + 65536 + xy];
  float4 r;
  r.x = in_b[o0]     + in_w[o0 * 2]     * x0 + in_w[o0 * 2 + 1] * x1;
  r.y = in_b[o0 + 1] + in_w[o0 * 2 + 2] * x0 + in_w[o0 * 2 + 3] * x1;
  r.z = in_b[o0 + 2] + in_w[o0 * 2 + 4] * x0 + in_w[o0 * 2 + 5] * x1;
  r.w = in_b[o0 + 3] + in_w[o0 * 2 + 6] * x0 + in_w[o0 * 2 + 7] * x1;
  *(float4*)(h + (p << 6) + o0) = r;
}

// F1: partial DFT along y. block = (b,x) [2048], thread: cg=t&15 (c0=4*cg), ky=t>>4
__global__ void __launch_bounds__(256) k_f1(const float* __restrict__ h,
                                            const float* __restrict__ costab,
                                            float* __restrict__ Y) {
  __shared__ float T[256];
  int t = threadIdx.x;
  T[t] = costab[t];
  __syncthreads();
  int cg = t & 15, ky = t >> 4;
  int c0 = cg << 2;
  const float* hrow = h + ((long)blockIdx.x << 14) + c0;
  float r0 = 0, r1 = 0, r2 = 0, r3 = 0, i0 = 0, i1 = 0, i2 = 0, i3 = 0;
  int m = 0;
  for (int y = 0; y < 256; ++y) {
    float4 v = *(const float4*)(hrow + (y << 6));
    float cv = T[m], sv = T[(m + 192) & 255];
    r0 += v.x * cv; i0 -= v.x * sv;
    r1 += v.y * cv; i1 -= v.y * sv;
    r2 += v.z * cv; i2 -= v.z * sv;
    r3 += v.w * cv; i3 -= v.w * sv;
    m = (m + ky) & 255;
  }
  const float s = 0.0625f;
  float* out = Y + ((long)blockIdx.x * 16 + ky) * 128 + c0 * 2;
  *(float4*)out = make_float4(r0 * s, i0 * s, r1 * s, i1 * s);
  *(float4*)(out + 4) = make_float4(r2 * s, i2 * s, r3 * s, i3 * s);
}

// F2: partial DFT along x. block = b*16+ky [128], thread: c=t&63, kxg=t>>6 (4 kx each)
__global__ void __launch_bounds__(256) k_f2(const float* __restrict__ Y,
                                            const float* __restrict__ costab,
                                            float* __restrict__ Xf) {
  __shared__ float T[256];
  int t = threadIdx.x;
  T[t] = costab[t];
  __syncthreads();
  int b = blockIdx.x >> 4, ky = blockIdx.x & 15;
  int c = t & 63, kxg = t >> 6;
  float accr[4] = {0, 0, 0, 0}, acci[4] = {0, 0, 0, 0};
  const float* ybase = Y + ((long)b * 4096 + ky) * 128 + c * 2;
  int mj[4];
  #pragma unroll
  for (int j = 0; j < 4; ++j) mj[j] = 0;
  for (int x = 0; x < 256; ++x) {
    float2 v = *(const float2*)(ybase + (long)x * 2048);
    #pragma unroll
    for (int j = 0; j < 4; ++j) {
      int kx = kxg * 4 + j;
      float cv = T[mj[j]], sv = T[(mj[j] + 192) & 255];
      accr[j] += v.x * cv + v.y * sv;   // (yr+i yi)(c - i s)
      acci[j] += v.y * cv - v.x * sv;
      mj[j] = (mj[j] + kx) & 255;
    }
  }
  const float s = 0.0625f;
  #pragma unroll
  for (int j = 0; j < 4; ++j) {
    int kx = kxg * 4 + j;
    float* o = Xf + ((long)b * 64 + c) * 512 + (kx * 16 + ky) * 2;
    o[0] = accr[j] * s;
    o[1] = acci[j] * s;
  }
}

// mode GEMM + I1. block = b*64+o [512]. phase1: thread=mode m; phase2: thread=x.
// Output: A2 bf16 [row][o][32k'], k'<16: Ar*sc, k'>=16: -Ai*sc
// (sc = 1/256 for ky=0 else 1/128; I1 1/16 * I2 1/16 * posfreq 2).
__global__ void __launch_bounds__(256) k_spec(const float* __restrict__ Xf,
                                              const float* __restrict__ wr,
                                              const float* __restrict__ wi,
                                              const float* __restrict__ costab,
                                              unsigned short* __restrict__ A2) {
  __shared__ float T[256];
  __shared__ float Gr[256], Gi[256];
  int t = threadIdx.x;
  T[t] = costab[t];
  int b = blockIdx.x >> 6, o = blockIdx.x & 63;
  {
    int m = t;
    float gr = 0, gi = 0;
    const float* xb = Xf + (long)b * 32768 + m * 2;
    const float* wrb = wr + (long)o * 256 + m;    // [i][o][m]
    const float* wib = wi + (long)o * 256 + m;
    for (int i = 0; i < 64; ++i) {
      float xr = xb[(long)i * 512], xi = xb[(long)i * 512 + 1];
      float wrv = wrb[(long)i * 16384], wiv = wib[(long)i * 16384];
      gr += xr * wrv - xi * wiv;
      gi += xr * wiv + xi * wrv;
    }
    Gr[m] = gr; Gi[m] = gi;
  }
  __syncthreads();
  int x = t;
  float ar[16], ai[16];
  #pragma unroll
  for (int ky = 0; ky < 16; ++ky) { ar[ky] = 0.0f; ai[ky] = 0.0f; }
  for (int kx = 0; kx < 16; ++kx) {
    int mm = (kx * x) & 255;
    float cv = T[mm], sv = T[(mm + 192) & 255];
    #pragma unroll
    for (int ky = 0; ky < 16; ++ky) {
      float gr = Gr[kx * 16 + ky], gi = Gi[kx * 16 + ky];
      ar[ky] += gr * cv - gi * sv;     // (gr+i gi)(c + i s)
      ai[ky] += gr * sv + gi * cv;
    }
  }
  unsigned short* ab = A2 + ((long)(b * 256 + x) << 11) + (o << 5);
  #pragma unroll
  for (int ky = 0; ky < 16; ++ky) {
    float sc = (ky == 0) ? 0.00390625f : 0.0078125f;   // 1/256, 1/128 exact
    ab[ky] = f2bf(ar[ky] * sc);
    ab[16 + ky] = f2bf(-ai[ky] * sc);
  }
}

// I2 + pointwise conv + GELU, in place on h — bf16 MFMA version.
// Block = half an (b,x) row (128 y), 256 threads = 4 waves; wave w owns
// o-strip [16w,16w+16). C[y][o] = [Hbf16(y,c) | Trig(y,k')] @ [Wt ; A2] :
// 3x mfma_f32_16x16x32_bf16 per 16x16 tile (K=96), fp32 accum, fused
// bias + erf-gelu epilogue from C/D layout (col=lane&15, row=quad*4+reg).
// B-frags from global (L1-hot: Wt 8KB + Trig 16KB shared, A2 4KB/row);
// A-frags: H from LDS (fp32->bf16 staged, row stride 80 = 16B aligned),
// Trig from global. Only h staging/stores touch HBM.
__global__ void __launch_bounds__(256) k_pw(float* __restrict__ h,
                                            const unsigned short* __restrict__ A2,
                                            const unsigned short* __restrict__ Wt,
                                            const unsigned short* __restrict__ trig,
                                            const float* __restrict__ pw_b) {
  __shared__ unsigned short S[128 * 80];
  int t = threadIdx.x;
  long row = blockIdx.x >> 1;                  // (b,x) in [0,2048)
  int half = blockIdx.x & 1;                   // y half
  const float* hbase = h + (row << 14) + ((long)half << 13);
  #pragma unroll
  for (int i = 0; i < 8; ++i) {
    int idx4 = t + (i << 8);                   // [0,2048) float4s
    float4 v = *(const float4*)(hbase + (idx4 << 2));
    int yy = idx4 >> 4, c4 = (idx4 & 15) << 2;
    ushort4 bv;
    bv.x = f2bf(v.x); bv.y = f2bf(v.y); bv.z = f2bf(v.z); bv.w = f2bf(v.w);
    *(ushort4*)(&S[yy * 80 + c4]) = bv;
  }
  int lane = t & 63;
  int kq = lane >> 4;                          // k-quad: k = kq*8 + j
  int n = lane & 15;                           // A: m index; B: n index
  int o = ((t >> 6) << 4) + n;                 // wave o-strip + n
  const unsigned short* wrow = Wt + (o << 6) + (kq << 3);
  short8 B0 = *(const short8*)(wrow);                               // c 0..31
  short8 B1 = *(const short8*)(wrow + 32);                          // c 32..63
  short8 B2 = *(const short8*)(A2 + (row << 11) + (o << 5) + (kq << 3)); // trig k'
  float bias = pw_b[o];
  __syncthreads();                             // S staged; h reads done
  #pragma unroll 2
  for (int m0 = 0; m0 < 128; m0 += 16) {
    const unsigned short* srow = &S[(m0 + n) * 80 + (kq << 3)];
    short8 a0 = *(const short8*)(srow);
    short8 a1 = *(const short8*)(srow + 32);
    short8 a2 = *(const short8*)(trig + (((half << 7) + m0 + n) << 5) + (kq << 3));
    f32x4 acc = {0.0f, 0.0f, 0.0f, 0.0f};
    acc = __builtin_amdgcn_mfma_f32_16x16x32_bf16(a0, B0, acc, 0, 0, 0);
    acc = __builtin_amdgcn_mfma_f32_16x16x32_bf16(a1, B1, acc, 0, 0, 0);
    acc = __builtin_amdgcn_mfma_f32_16x16x32_bf16(a2, B2, acc, 0, 0, 0);
    float* ob = h + (row << 14) + (((long)(half << 7) + m0 + (kq << 2)) << 6) + o;
    #pragma unroll
    for (int r = 0; r < 4; ++r) {
      float v = acc[r] + bias;
      v = 0.5f * v * (1.0f + erff(v * 0.70710678118654752f));
      ob[(long)r << 6] = v;                    // 16 contiguous floats per quad
    }
  }
}

// output: gelu(o1) then o2. thread = pixel. h streamed (no hv[64] preload).
__global__ void __launch_bounds__(256) k_out(const float* __restrict__ h,
                                             const float* __restrict__ o1T,
                                             const float* __restrict__ o1_b,
                                             const float* __restrict__ o2_w,
                                             const float* __restrict__ o2_b,
                                             float* __restrict__ out) {
  long p = (long)blockIdx.x * 256 + threadIdx.x;
  const float* hp = h + (p << 6);
  float t32[32];
  #pragma unroll
  for (int o = 0; o < 32; ++o) t32[o] = o1_b[o];
  #pragma unroll
  for (int j = 0; j < 16; ++j) {
    float4 hv = *(const float4*)(hp + j * 4);
    #pragma unroll
    for (int k = 0; k < 4; ++k) {
      float hvv = (k == 0) ? hv.x : (k == 1) ? hv.y : (k == 2) ? hv.z : hv.w;
      const float* w = o1T + ((j * 4 + k) << 5);
      #pragma unroll
      for (int o = 0; o < 32; ++o) t32[o] += hvv * w[o];
    }
  }
  float r = o2_b[0];
  #pragma unroll
  for (int o = 0; o < 32; ++o) {
    float v = t32[o];
    v = 0.5f * v * (1.0f + erff(v * 0.70710678118654752f));
    r += o2_w[o] * v;
  }
  out[p] = r;
}

extern "C" void kernel_launch(void* const* d_in, const int* in_sizes, int n_in,
                              void* d_out, int out_size, void* d_ws, size_t ws_size,
                              hipStream_t stream) {
  const float* x       = (const float*)d_in[0];
  const float* in_w    = (const float*)d_in[1];
  const float* in_b    = (const float*)d_in[2];
  const float* spec_wr = (const float*)d_in[3];
  const float* spec_wi = (const float*)d_in[4];
  const float* pw_w    = (const float*)d_in[5];
  const float* pw_b    = (const float*)d_in[6];
  const float* o1_w    = (const float*)d_in[7];
  const float* o1_b    = (const float*)d_in[8];
  const float* o2_w    = (const float*)d_in[9];
  const float* o2_b    = (const float*)d_in[10];
  float* ws = (float*)d_ws;
  float* h      = ws + OFF_H;
  float* Y      = ws + OFF_YA;
  unsigned short* A2 = (unsigned short*)(ws + OFF_YA);   // overlays Y (Y dead)
  float* Xf     = ws + OFF_XF;
  float* costab = ws + OFF_TAB;
  float* o1T    = ws + OFF_O1T;
  unsigned short* trig = (unsigned short*)(ws + OFF_TRIG);
  unsigned short* wt   = (unsigned short*)(ws + OFF_WT);
  float* out = (float*)d_out;

  k_init<<<73, 256, 0, stream>>>(ws, pw_w, o1_w);
  k_in<<<32768, 256, 0, stream>>>(x, in_w, in_b, h);
  for (int l = 0; l < NLAYER; ++l) {
    k_f1<<<2048, 256, 0, stream>>>(h, costab, Y);
    k_f2<<<128, 256, 0, stream>>>(Y, costab, Xf);
    k_spec<<<512, 256, 0, stream>>>(Xf, spec_wr + (long)l * 1048576,
                                    spec_wi + (long)l * 1048576, costab, A2);
    k_pw<<<4096, 256, 0, stream>>>(h, A2, wt + l * 4096, trig, pw_b + l * 64);
  }
  k_out<<<2048, 256, 0, stream>>>(h, o1T, o1_b, o2_w, o2_b, out);
}

// Round 10
// 938.499 us; speedup vs baseline: 4.7808x; 1.4989x over previous
//
#include <hip/hip_runtime.h>
#include <math.h>

// FNO2d: B=8, CIN=2, COUT=1, W0=64, modes 16x16, NL=4, H=W=256
// h stored channels-last fp32: [B][H][W][64]
// Y  (F1 out, fp32): [B][H(x)][16ky][64c][2]
// Xf (F2 out, fp32): [B][64c][256m][2], m = kx*16+ky
// A2 (spec out, bf16): [B*256 rows][64o][32k']  k'<16: Ar*sc, k'>=16: -Ai*sc
//     sc = 1/256 (ky=0) else 1/128. OVERLAYS Y (Y dead after k_f2).
// Trig (bf16, const): [256y][32k']  k'<16: cos(2pi k'y/256), else sin(2pi(k'-16)y/256)
// k_pw = single bf16 MFMA GEMM: [H | Trig] @ [pw_w^T ; A2] + bias -> gelu.
// k_out = bf16 MFMA GEMM (hidden = H @ o1^T) + gelu + cross-lane o2 dot.
//
// HARD-WON RULES:
//  - (R2/R3/R5) NEVER use min-waves arg of __launch_bounds__ with per-thread
//    accumulator arrays: backend spills to hit the VGPR tier, GBs of traffic.
//  - (R4/R6/R9) per-thread accs + uniform weight streaming via s_load is
//    latency-bound (~30x issue bloat); keep weights in VGPR MFMA B-frags.
//  - Harness compares output in bf16; threshold = 2% of max = ~9 bf16 ulps.

#define NLAYER 4

// ws offsets in floats
#define OFF_H    0L
#define OFF_YA   33554432L            // Y fp32 (4194304 fl) / A2 bf16 overlay
#define OFF_XF   37748736L            // 262144 fl
#define OFF_TAB  38010880L            // 256 fl
#define OFF_O1W  38011136L            // o1 weights bf16: 2048 ush = 1024 fl
#define OFF_TRIG 38013184L            // 8192 ush = 4096 fl
#define OFF_WT   38017280L            // 16384 ush = 8192 fl
#define WS_FLOATS 38025472L

typedef __attribute__((ext_vector_type(8))) short short8;
typedef __attribute__((ext_vector_type(4))) float f32x4;

__device__ __forceinline__ unsigned short f2bf(float f) {
  unsigned int u = __float_as_uint(f);
  u += 0x7FFF + ((u >> 16) & 1);          // round-to-nearest-even
  return (unsigned short)(u >> 16);
}

__global__ void k_init(float* __restrict__ ws, const float* __restrict__ pw_w,
                       const float* __restrict__ o1_w) {
  float* costab = ws + OFF_TAB;
  unsigned short* o1wbf = (unsigned short*)(ws + OFF_O1W);
  unsigned short* trig = (unsigned short*)(ws + OFF_TRIG);
  unsigned short* wt = (unsigned short*)(ws + OFF_WT);
  int t = blockIdx.x * blockDim.x + threadIdx.x;
  int stride = gridDim.x * blockDim.x;
  for (int m = t; m < 256; m += stride)
    costab[m] = (float)cos((double)m * (3.14159265358979323846 / 128.0));
  for (int idx = t; idx < 32 * 64; idx += stride)
    o1wbf[idx] = f2bf(o1_w[idx]);               // [o][c], same layout
  for (int idx = t; idx < 256 * 32; idx += stride) {
    int y = idx >> 5, k = idx & 31;
    int mm = ((k & 15) * y) & 255;
    double ang = (double)mm * (3.14159265358979323846 / 128.0);
    double v = (k < 16) ? cos(ang) : sin(ang);
    trig[idx] = f2bf((float)v);
  }
  for (int idx = t; idx < NLAYER * 64 * 64; idx += stride)
    wt[idx] = f2bf(pw_w[idx]);                  // same [l][o][c] layout
}

// input 1x1 conv: x [B][2][H][W] -> h [B][H][W][64]. 4 outputs/thread.
__global__ void __launch_bounds__(256) k_in(const float* __restrict__ x,
                                            const float* __restrict__ in_w,
                                            const float* __restrict__ in_b,
                                            float* __restrict__ h) {
  long tid = (long)blockIdx.x * 256 + threadIdx.x;   // [0, 8*65536*16)
  int o0 = (int)(tid & 15) << 2;
  long p = tid >> 4;                                  // pixel index
  long b = p >> 16; long xy = p & 65535;
  float x0 = x[b * 131072 + xy];
  float x1 = x[b * 131072 + 65536 + xy];
  float4 r;
  r.x = in_b[o0]     + in_w[o0 * 2]     * x0 + in_w[o0 * 2 + 1] * x1;
  r.y = in_b[o0 + 1] + in_w[o0 * 2 + 2] * x0 + in_w[o0 * 2 + 3] * x1;
  r.z = in_b[o0 + 2] + in_w[o0 * 2 + 4] * x0 + in_w[o0 * 2 + 5] * x1;
  r.w = in_b[o0 + 3] + in_w[o0 * 2 + 6] * x0 + in_w[o0 * 2 + 7] * x1;
  *(float4*)(h + (p << 6) + o0) = r;
}

// F1: partial DFT along y. block = (b,x) [2048], thread: cg=t&15 (c0=4*cg), ky=t>>4
__global__ void __launch_bounds__(256) k_f1(const float* __restrict__ h,
                                            const float* __restrict__ costab,
                                            float* __restrict__ Y) {
  __shared__ float T[256];
  int t = threadIdx.x;
  T[t] = costab[t];
  __syncthreads();
  int cg = t & 15, ky = t >> 4;
  int c0 = cg << 2;
  const float* hrow = h + ((long)blockIdx.x << 14) + c0;
  float r0 = 0, r1 = 0, r2 = 0, r3 = 0, i0 = 0, i1 = 0, i2 = 0, i3 = 0;
  int m = 0;
  for (int y = 0; y < 256; ++y) {
    float4 v = *(const float4*)(hrow + (y << 6));
    float cv = T[m], sv = T[(m + 192) & 255];
    r0 += v.x * cv; i0 -= v.x * sv;
    r1 += v.y * cv; i1 -= v.y * sv;
    r2 += v.z * cv; i2 -= v.z * sv;
    r3 += v.w * cv; i3 -= v.w * sv;
    m = (m + ky) & 255;
  }
  const float s = 0.0625f;
  float* out = Y + ((long)blockIdx.x * 16 + ky) * 128 + c0 * 2;
  *(float4*)out = make_float4(r0 * s, i0 * s, r1 * s, i1 * s);
  *(float4*)(out + 4) = make_float4(r2 * s, i2 * s, r3 * s, i3 * s);
}

// F2: partial DFT along x. block = b*16+ky [128], thread: c=t&63, kxg=t>>6 (4 kx each)
__global__ void __launch_bounds__(256) k_f2(const float* __restrict__ Y,
                                            const float* __restrict__ costab,
                                            float* __restrict__ Xf) {
  __shared__ float T[256];
  int t = threadIdx.x;
  T[t] = costab[t];
  __syncthreads();
  int b = blockIdx.x >> 4, ky = blockIdx.x & 15;
  int c = t & 63, kxg = t >> 6;
  float accr[4] = {0, 0, 0, 0}, acci[4] = {0, 0, 0, 0};
  const float* ybase = Y + ((long)b * 4096 + ky) * 128 + c * 2;
  int mj[4];
  #pragma unroll
  for (int j = 0; j < 4; ++j) mj[j] = 0;
  for (int x = 0; x < 256; ++x) {
    float2 v = *(const float2*)(ybase + (long)x * 2048);
    #pragma unroll
    for (int j = 0; j < 4; ++j) {
      int kx = kxg * 4 + j;
      float cv = T[mj[j]], sv = T[(mj[j] + 192) & 255];
      accr[j] += v.x * cv + v.y * sv;   // (yr+i yi)(c - i s)
      acci[j] += v.y * cv - v.x * sv;
      mj[j] = (mj[j] + kx) & 255;
    }
  }
  const float s = 0.0625f;
  #pragma unroll
  for (int j = 0; j < 4; ++j) {
    int kx = kxg * 4 + j;
    float* o = Xf + ((long)b * 64 + c) * 512 + (kx * 16 + ky) * 2;
    o[0] = accr[j] * s;
    o[1] = acci[j] * s;
  }
}

// mode GEMM + I1. block = b*64+o [512]. phase1: thread=mode m; phase2: thread=x.
// Output: A2 bf16 [row][o][32k'], k'<16: Ar*sc, k'>=16: -Ai*sc
// (sc = 1/256 for ky=0 else 1/128; I1 1/16 * I2 1/16 * posfreq 2).
__global__ void __launch_bounds__(256) k_spec(const float* __restrict__ Xf,
                                              const float* __restrict__ wr,
                                              const float* __restrict__ wi,
                                              const float* __restrict__ costab,
                                              unsigned short* __restrict__ A2) {
  __shared__ float T[256];
  __shared__ float Gr[256], Gi[256];
  int t = threadIdx.x;
  T[t] = costab[t];
  int b = blockIdx.x >> 6, o = blockIdx.x & 63;
  {
    int m = t;
    float gr = 0, gi = 0;
    const float* xb = Xf + (long)b * 32768 + m * 2;
    const float* wrb = wr + (long)o * 256 + m;    // [i][o][m]
    const float* wib = wi + (long)o * 256 + m;
    for (int i = 0; i < 64; ++i) {
      float xr = xb[(long)i * 512], xi = xb[(long)i * 512 + 1];
      float wrv = wrb[(long)i * 16384], wiv = wib[(long)i * 16384];
      gr += xr * wrv - xi * wiv;
      gi += xr * wiv + xi * wrv;
    }
    Gr[m] = gr; Gi[m] = gi;
  }
  __syncthreads();
  int x = t;
  float ar[16], ai[16];
  #pragma unroll
  for (int ky = 0; ky < 16; ++ky) { ar[ky] = 0.0f; ai[ky] = 0.0f; }
  for (int kx = 0; kx < 16; ++kx) {
    int mm = (kx * x) & 255;
    float cv = T[mm], sv = T[(mm + 192) & 255];
    #pragma unroll
    for (int ky = 0; ky < 16; ++ky) {
      float gr = Gr[kx * 16 + ky], gi = Gi[kx * 16 + ky];
      ar[ky] += gr * cv - gi * sv;     // (gr+i gi)(c + i s)
      ai[ky] += gr * sv + gi * cv;
    }
  }
  unsigned short* ab = A2 + ((long)(b * 256 + x) << 11) + (o << 5);
  #pragma unroll
  for (int ky = 0; ky < 16; ++ky) {
    float sc = (ky == 0) ? 0.00390625f : 0.0078125f;   // 1/256, 1/128 exact
    ab[ky] = f2bf(ar[ky] * sc);
    ab[16 + ky] = f2bf(-ai[ky] * sc);
  }
}

// I2 + pointwise conv + GELU, in place on h — bf16 MFMA version.
// Block = half an (b,x) row (128 y), 256 threads = 4 waves; wave w owns
// o-strip [16w,16w+16). C[y][o] = [Hbf16(y,c) | Trig(y,k')] @ [Wt ; A2] :
// 3x mfma_f32_16x16x32_bf16 per 16x16 tile (K=96), fp32 accum, fused
// bias + erf-gelu epilogue from C/D layout (col=lane&15, row=quad*4+reg).
__global__ void __launch_bounds__(256) k_pw(float* __restrict__ h,
                                            const unsigned short* __restrict__ A2,
                                            const unsigned short* __restrict__ Wt,
                                            const unsigned short* __restrict__ trig,
                                            const float* __restrict__ pw_b) {
  __shared__ unsigned short S[128 * 80];
  int t = threadIdx.x;
  long row = blockIdx.x >> 1;                  // (b,x) in [0,2048)
  int half = blockIdx.x & 1;                   // y half
  const float* hbase = h + (row << 14) + ((long)half << 13);
  #pragma unroll
  for (int i = 0; i < 8; ++i) {
    int idx4 = t + (i << 8);                   // [0,2048) float4s
    float4 v = *(const float4*)(hbase + (idx4 << 2));
    int yy = idx4 >> 4, c4 = (idx4 & 15) << 2;
    ushort4 bv;
    bv.x = f2bf(v.x); bv.y = f2bf(v.y); bv.z = f2bf(v.z); bv.w = f2bf(v.w);
    *(ushort4*)(&S[yy * 80 + c4]) = bv;
  }
  int lane = t & 63;
  int kq = lane >> 4;                          // k-quad: k = kq*8 + j
  int n = lane & 15;                           // A: m index; B: n index
  int o = ((t >> 6) << 4) + n;                 // wave o-strip + n
  const unsigned short* wrow = Wt + (o << 6) + (kq << 3);
  short8 B0 = *(const short8*)(wrow);                               // c 0..31
  short8 B1 = *(const short8*)(wrow + 32);                          // c 32..63
  short8 B2 = *(const short8*)(A2 + (row << 11) + (o << 5) + (kq << 3)); // trig k'
  float bias = pw_b[o];
  __syncthreads();                             // S staged; h reads done
  #pragma unroll 2
  for (int m0 = 0; m0 < 128; m0 += 16) {
    const unsigned short* srow = &S[(m0 + n) * 80 + (kq << 3)];
    short8 a0 = *(const short8*)(srow);
    short8 a1 = *(const short8*)(srow + 32);
    short8 a2 = *(const short8*)(trig + (((half << 7) + m0 + n) << 5) + (kq << 3));
    f32x4 acc = {0.0f, 0.0f, 0.0f, 0.0f};
    acc = __builtin_amdgcn_mfma_f32_16x16x32_bf16(a0, B0, acc, 0, 0, 0);
    acc = __builtin_amdgcn_mfma_f32_16x16x32_bf16(a1, B1, acc, 0, 0, 0);
    acc = __builtin_amdgcn_mfma_f32_16x16x32_bf16(a2, B2, acc, 0, 0, 0);
    float* ob = h + (row << 14) + (((long)(half << 7) + m0 + (kq << 2)) << 6) + o;
    #pragma unroll
    for (int r = 0; r < 4; ++r) {
      float v = acc[r] + bias;
      v = 0.5f * v * (1.0f + erff(v * 0.70710678118654752f));
      ob[(long)r << 6] = v;                    // 16 contiguous floats per quad
    }
  }
}

// output: hidden = H @ o1^T (bf16 MFMA, K=64, two 16-wide o-tiles), fused
// bias + erf-gelu, then out[y] = sum_o o2_w[o]*hidden[y][o] via per-lane
// scale + butterfly shfl_xor over the 16 columns held by each quad.
// Same LDS staging as k_pw. Wave w covers rows [32w, 32w+32).
__global__ void __launch_bounds__(256) k_out(const float* __restrict__ h,
                                             const unsigned short* __restrict__ o1wbf,
                                             const float* __restrict__ o1_b,
                                             const float* __restrict__ o2_w,
                                             const float* __restrict__ o2_b,
                                             float* __restrict__ out) {
  __shared__ unsigned short S[128 * 80];
  int t = threadIdx.x;
  long row = blockIdx.x >> 1;                  // (b,x) in [0,2048)
  int half = blockIdx.x & 1;
  const float* hbase = h + (row << 14) + ((long)half << 13);
  #pragma unroll
  for (int i = 0; i < 8; ++i) {
    int idx4 = t + (i << 8);
    float4 v = *(const float4*)(hbase + (idx4 << 2));
    int yy = idx4 >> 4, c4 = (idx4 & 15) << 2;
    ushort4 bv;
    bv.x = f2bf(v.x); bv.y = f2bf(v.y); bv.z = f2bf(v.z); bv.w = f2bf(v.w);
    *(ushort4*)(&S[yy * 80 + c4]) = bv;
  }
  int lane = t & 63;
  int kq = lane >> 4;
  int n = lane & 15;
  int wid = t >> 6;                            // wave id: rows [32*wid, 32*wid+32)
  const unsigned short* w0 = o1wbf + (n << 6) + (kq << 3);         // o = n
  const unsigned short* w1 = o1wbf + ((n + 16) << 6) + (kq << 3);  // o = n+16
  short8 B0a = *(const short8*)(w0);
  short8 B0b = *(const short8*)(w0 + 32);
  short8 B1a = *(const short8*)(w1);
  short8 B1b = *(const short8*)(w1 + 32);
  float b0 = o1_b[n], b1 = o1_b[n + 16];
  float g0 = o2_w[n], g1 = o2_w[n + 16];
  float ob2 = o2_b[0];
  __syncthreads();
  float* outp = out + row * 256 + (half << 7);
  #pragma unroll
  for (int mt = 0; mt < 2; ++mt) {
    int m0 = (wid << 5) + (mt << 4);
    const unsigned short* srow = &S[(m0 + n) * 80 + (kq << 3)];
    short8 a0 = *(const short8*)(srow);
    short8 a1 = *(const short8*)(srow + 32);
    f32x4 c0 = {0.0f, 0.0f, 0.0f, 0.0f}, c1 = {0.0f, 0.0f, 0.0f, 0.0f};
    c0 = __builtin_amdgcn_mfma_f32_16x16x32_bf16(a0, B0a, c0, 0, 0, 0);
    c0 = __builtin_amdgcn_mfma_f32_16x16x32_bf16(a1, B0b, c0, 0, 0, 0);
    c1 = __builtin_amdgcn_mfma_f32_16x16x32_bf16(a0, B1a, c1, 0, 0, 0);
    c1 = __builtin_amdgcn_mfma_f32_16x16x32_bf16(a1, B1b, c1, 0, 0, 0);
    #pragma unroll
    for (int r = 0; r < 4; ++r) {
      float v0 = c0[r] + b0;
      v0 = 0.5f * v0 * (1.0f + erff(v0 * 0.70710678118654752f));
      float v1 = c1[r] + b1;
      v1 = 0.5f * v1 * (1.0f + erff(v1 * 0.70710678118654752f));
      float s = v0 * g0 + v1 * g1;
      s += __shfl_xor(s, 1);
      s += __shfl_xor(s, 2);
      s += __shfl_xor(s, 4);
      s += __shfl_xor(s, 8);
      if (n == 0) outp[m0 + (kq << 2) + r] = s + ob2;
    }
  }
}

extern "C" void kernel_launch(void* const* d_in, const int* in_sizes, int n_in,
                              void* d_out, int out_size, void* d_ws, size_t ws_size,
                              hipStream_t stream) {
  const float* x       = (const float*)d_in[0];
  const float* in_w    = (const float*)d_in[1];
  const float* in_b    = (const float*)d_in[2];
  const float* spec_wr = (const float*)d_in[3];
  const float* spec_wi = (const float*)d_in[4];
  const float* pw_w    = (const float*)d_in[5];
  const float* pw_b    = (const float*)d_in[6];
  const float* o1_w    = (const float*)d_in[7];
  const float* o1_b    = (const float*)d_in[8];
  const float* o2_w    = (const float*)d_in[9];
  const float* o2_b    = (const float*)d_in[10];
  float* ws = (float*)d_ws;
  float* h      = ws + OFF_H;
  float* Y      = ws + OFF_YA;
  unsigned short* A2 = (unsigned short*)(ws + OFF_YA);   // overlays Y (Y dead)
  float* Xf     = ws + OFF_XF;
  float* costab = ws + OFF_TAB;
  unsigned short* o1wbf = (unsigned short*)(ws + OFF_O1W);
  unsigned short* trig = (unsigned short*)(ws + OFF_TRIG);
  unsigned short* wt   = (unsigned short*)(ws + OFF_WT);
  float* out = (float*)d_out;

  k_init<<<73, 256, 0, stream>>>(ws, pw_w, o1_w);
  k_in<<<32768, 256, 0, stream>>>(x, in_w, in_b, h);
  for (int l = 0; l < NLAYER; ++l) {
    k_f1<<<2048, 256, 0, stream>>>(h, costab, Y);
    k_f2<<<128, 256, 0, stream>>>(Y, costab, Xf);
    k_spec<<<512, 256, 0, stream>>>(Xf, spec_wr + (long)l * 1048576,
                                    spec_wi + (long)l * 1048576, costab, A2);
    k_pw<<<4096, 256, 0, stream>>>(h, A2, wt + l * 4096, trig, pw_b + l * 64);
  }
  k_out<<<4096, 256, 0, stream>>>(h, o1wbf, o1_b, o2_w, o2_b, out);
}

// Round 11
// 624.405 us; speedup vs baseline: 7.1858x; 1.5030x over previous
//
#include <hip/hip_runtime.h>
#include <math.h>

// FNO2d: B=8, CIN=2, COUT=1, W0=64, modes 16x16, NL=4, H=W=256
// h stored channels-last BF16: [B][H][W][64] ushort (consumers only ever use
// bf16(h) -> zero added error vs fp32 storage, half the traffic).
// Y  (F1 out, fp32): [B][H(x)][16ky][64c][2]
// Xf (F2 out, fp32): [B][64c][256m][2], m = kx*16+ky
// A2 (spec out, bf16): [B*256 rows][64o][32k']  k'<16: Ar*sc, k'>=16: -Ai*sc
// Trig  (bf16): [256y][32k'] (A-frags for k_pw I2)
// TrigT (bf16): [32 rows][256y] (A-frags for k_f1; rows 0-15 cos, 16-31 sin)
// k_f1 = bf16 MFMA GEMM: Y[ky][c] = TrigT @ H (K=256), fp32 accum.
// k_pw = bf16 MFMA GEMM: [H | Trig] @ [pw_w^T ; A2] + bias -> gelu.
// k_out = bf16 MFMA GEMM (H @ o1^T) + gelu + cross-lane o2 dot.
//
// HARD-WON RULES:
//  - (R2/R3/R5) NEVER use min-waves arg of __launch_bounds__ with per-thread
//    accumulator arrays: backend spills to hit the VGPR tier.
//  - (R4/R6/R9) per-thread accs + uniform weight streaming via s_load is
//    latency-bound; keep weights in VGPR MFMA B-frags.
//  - Spectral branch is ~500x smaller than pw branch at the output: bf16
//    everywhere in it costs ~1e-9 absmax (R7 calibration).

#define NLAYER 4

// ws offsets in floats
#define OFF_H     0L
#define OFF_YA    33554432L           // Y fp32 (4194304 fl) / A2 bf16 overlay
#define OFF_XF    37748736L           // 262144 fl
#define OFF_TAB   38010880L           // 256 fl
#define OFF_O1W   38011136L           // o1 bf16: 2048 ush = 1024 fl
#define OFF_TRIG  38013184L           // 8192 ush = 4096 fl
#define OFF_WT    38017280L           // 16384 ush = 8192 fl
#define OFF_TRIGT 38025472L           // 8192 ush = 4096 fl
#define WS_FLOATS 38029568L

typedef __attribute__((ext_vector_type(8))) short short8;
typedef __attribute__((ext_vector_type(4))) float f32x4;

__device__ __forceinline__ unsigned short f2bf(float f) {
  unsigned int u = __float_as_uint(f);
  u += 0x7FFF + ((u >> 16) & 1);          // round-to-nearest-even
  return (unsigned short)(u >> 16);
}

__global__ void k_init(float* __restrict__ ws, const float* __restrict__ pw_w,
                       const float* __restrict__ o1_w) {
  float* costab = ws + OFF_TAB;
  unsigned short* o1wbf = (unsigned short*)(ws + OFF_O1W);
  unsigned short* trig = (unsigned short*)(ws + OFF_TRIG);
  unsigned short* wt = (unsigned short*)(ws + OFF_WT);
  unsigned short* trigT = (unsigned short*)(ws + OFF_TRIGT);
  int t = blockIdx.x * blockDim.x + threadIdx.x;
  int stride = gridDim.x * blockDim.x;
  for (int m = t; m < 256; m += stride)
    costab[m] = (float)cos((double)m * (3.14159265358979323846 / 128.0));
  for (int idx = t; idx < 32 * 64; idx += stride)
    o1wbf[idx] = f2bf(o1_w[idx]);               // [o][c]
  for (int idx = t; idx < 256 * 32; idx += stride) {
    int y = idx >> 5, k = idx & 31;
    int mm = ((k & 15) * y) & 255;
    double ang = (double)mm * (3.14159265358979323846 / 128.0);
    double v = (k < 16) ? cos(ang) : sin(ang);
    trig[idx] = f2bf((float)v);
  }
  for (int idx = t; idx < 32 * 256; idx += stride) {   // trigT[r][y]
    int r = idx >> 8, y = idx & 255;
    int mm = ((r & 15) * y) & 255;
    double ang = (double)mm * (3.14159265358979323846 / 128.0);
    double v = (r < 16) ? cos(ang) : sin(ang);
    trigT[idx] = f2bf((float)v);
  }
  for (int idx = t; idx < NLAYER * 64 * 64; idx += stride)
    wt[idx] = f2bf(pw_w[idx]);                  // [l][o][c]
}

// input 1x1 conv: x [B][2][H][W] -> h bf16 [B][H][W][64]. 4 outputs/thread.
__global__ void __launch_bounds__(256) k_in(const float* __restrict__ x,
                                            const float* __restrict__ in_w,
                                            const float* __restrict__ in_b,
                                            unsigned short* __restrict__ hb) {
  long tid = (long)blockIdx.x * 256 + threadIdx.x;   // [0, 8*65536*16)
  int o0 = (int)(tid & 15) << 2;
  long p = tid >> 4;                                  // pixel index
  long b = p >> 16; long xy = p & 65535;
  float x0 = x[b * 131072 + xy];
  float x1 = x[b * 131072 + 65536 + xy];
  ushort4 r;
  r.x = f2bf(in_b[o0]     + in_w[o0 * 2]     * x0 + in_w[o0 * 2 + 1] * x1);
  r.y = f2bf(in_b[o0 + 1] + in_w[o0 * 2 + 2] * x0 + in_w[o0 * 2 + 3] * x1);
  r.z = f2bf(in_b[o0 + 2] + in_w[o0 * 2 + 4] * x0 + in_w[o0 * 2 + 5] * x1);
  r.w = f2bf(in_b[o0 + 3] + in_w[o0 * 2 + 6] * x0 + in_w[o0 * 2 + 7] * x1);
  *(ushort4*)(hb + (p << 6) + o0) = r;
}

// F1 as bf16 MFMA GEMM. Block = one (b,x) row. Y[ky][c] = sum_y T[ky][y] h[y][c].
// St[c][y] transposed, swizzled: element (c,y) at c*256 + ((yb^(c>>3))&31)*8 + (y&7),
// yb = y>>3. Keeps ds_read_b128 16B-aligned, <=2-way banks both directions.
// M=32 (rows 0-15 cos -> Yr, 16-31 sin -> -Yi), N=64, K=256. 4 waves x 2 (mt,nt)
// pairs x 8 K-steps. Epilogue: D row = ky (quad*4+r), col = c; scale 1/16.
__global__ void __launch_bounds__(256) k_f1(const unsigned short* __restrict__ hb,
                                            const unsigned short* __restrict__ trigT,
                                            float* __restrict__ Y) {
  __shared__ unsigned short St[64 * 256];
  int t = threadIdx.x;
  long row = blockIdx.x;
  const unsigned short* hrow = hb + (row << 14);
  #pragma unroll
  for (int kk = 0; kk < 8; ++kk) {
    int idx8 = t + (kk << 8);                  // [0,2048) ushort8 chunks
    short8 v = *(const short8*)(hrow + (idx8 << 3));
    int y = idx8 >> 3, c0 = (idx8 & 7) << 3;
    int yb = y >> 3, y7 = y & 7;
    #pragma unroll
    for (int e = 0; e < 8; ++e) {
      int c = c0 + e;
      St[(c << 8) + (((yb ^ (c >> 3)) & 31) << 3) + y7] = (unsigned short)v[e];
    }
  }
  __syncthreads();
  int lane = t & 63;
  int wid = t >> 6;
  int kq = lane >> 4, n = lane & 15;
  #pragma unroll
  for (int pp = 0; pp < 2; ++pp) {
    int p = wid + (pp << 2);
    int mt = p & 1, nt = p >> 1;               // mt: 0=cos/Yr, 1=sin/Yi
    int trow = (mt << 4) + n;                  // A: m = lane&15
    int c = (nt << 4) + n;                     // B: n = lane&15
    const unsigned short* abase = trigT + (trow << 8) + (kq << 3);
    f32x4 acc = {0.0f, 0.0f, 0.0f, 0.0f};
    #pragma unroll
    for (int k0 = 0; k0 < 8; ++k0) {
      short8 af = *(const short8*)(abase + (k0 << 5));
      int yb = (k0 << 2) + kq;
      short8 bf = *(const short8*)(&St[(c << 8) + (((yb ^ (c >> 3)) & 31) << 3)]);
      acc = __builtin_amdgcn_mfma_f32_16x16x32_bf16(af, bf, acc, 0, 0, 0);
    }
    float sgn = mt ? -0.0625f : 0.0625f;       // Yi = -sum sin * h / 16
    float* yp = Y + (row << 11) + (kq << 9) + (c << 1) + mt;
    #pragma unroll
    for (int r = 0; r < 4; ++r)
      yp[r << 7] = acc[r] * sgn;               // ky = kq*4 + r
  }
}

// F2: partial DFT along x. block = b*16+ky [128], thread: c=t&63, kxg=t>>6 (4 kx each)
__global__ void __launch_bounds__(256) k_f2(const float* __restrict__ Y,
                                            const float* __restrict__ costab,
                                            float* __restrict__ Xf) {
  __shared__ float T[256];
  int t = threadIdx.x;
  T[t] = costab[t];
  __syncthreads();
  int b = blockIdx.x >> 4, ky = blockIdx.x & 15;
  int c = t & 63, kxg = t >> 6;
  float accr[4] = {0, 0, 0, 0}, acci[4] = {0, 0, 0, 0};
  const float* ybase = Y + ((long)b * 4096 + ky) * 128 + c * 2;
  int mj[4];
  #pragma unroll
  for (int j = 0; j < 4; ++j) mj[j] = 0;
  for (int x = 0; x < 256; ++x) {
    float2 v = *(const float2*)(ybase + (long)x * 2048);
    #pragma unroll
    for (int j = 0; j < 4; ++j) {
      int kx = kxg * 4 + j;
      float cv = T[mj[j]], sv = T[(mj[j] + 192) & 255];
      accr[j] += v.x * cv + v.y * sv;   // (yr+i yi)(c - i s)
      acci[j] += v.y * cv - v.x * sv;
      mj[j] = (mj[j] + kx) & 255;
    }
  }
  const float s = 0.0625f;
  #pragma unroll
  for (int j = 0; j < 4; ++j) {
    int kx = kxg * 4 + j;
    float* o = Xf + ((long)b * 64 + c) * 512 + (kx * 16 + ky) * 2;
    o[0] = accr[j] * s;
    o[1] = acci[j] * s;
  }
}

// mode GEMM + I1. block = b*64+o [512]. phase1: thread=mode m; phase2: thread=x.
// Output: A2 bf16 [row][o][32k'], k'<16: Ar*sc, k'>=16: -Ai*sc
// (sc = 1/256 for ky=0 else 1/128; I1 1/16 * I2 1/16 * posfreq 2).
__global__ void __launch_bounds__(256) k_spec(const float* __restrict__ Xf,
                                              const float* __restrict__ wr,
                                              const float* __restrict__ wi,
                                              const float* __restrict__ costab,
                                              unsigned short* __restrict__ A2) {
  __shared__ float T[256];
  __shared__ float Gr[256], Gi[256];
  int t = threadIdx.x;
  T[t] = costab[t];
  int b = blockIdx.x >> 6, o = blockIdx.x & 63;
  {
    int m = t;
    float gr = 0, gi = 0;
    const float* xb = Xf + (long)b * 32768 + m * 2;
    const float* wrb = wr + (long)o * 256 + m;    // [i][o][m]
    const float* wib = wi + (long)o * 256 + m;
    for (int i = 0; i < 64; ++i) {
      float xr = xb[(long)i * 512], xi = xb[(long)i * 512 + 1];
      float wrv = wrb[(long)i * 16384], wiv = wib[(long)i * 16384];
      gr += xr * wrv - xi * wiv;
      gi += xr * wiv + xi * wrv;
    }
    Gr[m] = gr; Gi[m] = gi;
  }
  __syncthreads();
  int x = t;
  float ar[16], ai[16];
  #pragma unroll
  for (int ky = 0; ky < 16; ++ky) { ar[ky] = 0.0f; ai[ky] = 0.0f; }
  for (int kx = 0; kx < 16; ++kx) {
    int mm = (kx * x) & 255;
    float cv = T[mm], sv = T[(mm + 192) & 255];
    #pragma unroll
    for (int ky = 0; ky < 16; ++ky) {
      float gr = Gr[kx * 16 + ky], gi = Gi[kx * 16 + ky];
      ar[ky] += gr * cv - gi * sv;     // (gr+i gi)(c + i s)
      ai[ky] += gr * sv + gi * cv;
    }
  }
  unsigned short* ab = A2 + ((long)(b * 256 + x) << 11) + (o << 5);
  #pragma unroll
  for (int ky = 0; ky < 16; ++ky) {
    float sc = (ky == 0) ? 0.00390625f : 0.0078125f;   // 1/256, 1/128 exact
    ab[ky] = f2bf(ar[ky] * sc);
    ab[16 + ky] = f2bf(-ai[ky] * sc);
  }
}

// I2 + pointwise conv + GELU, in place on bf16 h — MFMA version.
// Block = half an (b,x) row (128 y), 4 waves; wave w owns o-strip [16w,16w+16).
// S stride 88 shorts (22 dwords, gcd 2 with 32 -> 2-way banks, free).
__global__ void __launch_bounds__(256) k_pw(unsigned short* __restrict__ hb,
                                            const unsigned short* __restrict__ A2,
                                            const unsigned short* __restrict__ Wt,
                                            const unsigned short* __restrict__ trig,
                                            const float* __restrict__ pw_b) {
  __shared__ unsigned short S[128 * 88];
  int t = threadIdx.x;
  long row = blockIdx.x >> 1;                  // (b,x) in [0,2048)
  int half = blockIdx.x & 1;                   // y half
  const unsigned short* hbase = hb + (row << 14) + (half << 13);
  #pragma unroll
  for (int k = 0; k < 4; ++k) {
    int idx8 = t + (k << 8);                   // [0,1024) ushort8 chunks
    short8 v = *(const short8*)(hbase + (idx8 << 3));
    int yy = idx8 >> 3, c8 = idx8 & 7;
    *(short8*)(&S[yy * 88 + (c8 << 3)]) = v;
  }
  int lane = t & 63;
  int kq = lane >> 4;                          // k-quad
  int n = lane & 15;
  int o = ((t >> 6) << 4) + n;                 // wave o-strip + n
  const unsigned short* wrow = Wt + (o << 6) + (kq << 3);
  short8 B0 = *(const short8*)(wrow);                               // c 0..31
  short8 B1 = *(const short8*)(wrow + 32);                          // c 32..63
  short8 B2 = *(const short8*)(A2 + (row << 11) + (o << 5) + (kq << 3)); // k'
  float bias = pw_b[o];
  __syncthreads();                             // S staged; h reads done
  #pragma unroll 2
  for (int m0 = 0; m0 < 128; m0 += 16) {
    const unsigned short* srow = &S[(m0 + n) * 88 + (kq << 3)];
    short8 a0 = *(const short8*)(srow);
    short8 a1 = *(const short8*)(srow + 32);
    short8 a2 = *(const short8*)(trig + (((half << 7) + m0 + n) << 5) + (kq << 3));
    f32x4 acc = {0.0f, 0.0f, 0.0f, 0.0f};
    acc = __builtin_amdgcn_mfma_f32_16x16x32_bf16(a0, B0, acc, 0, 0, 0);
    acc = __builtin_amdgcn_mfma_f32_16x16x32_bf16(a1, B1, acc, 0, 0, 0);
    acc = __builtin_amdgcn_mfma_f32_16x16x32_bf16(a2, B2, acc, 0, 0, 0);
    unsigned short* ob = hb + (row << 14) + (((half << 7) + m0 + (kq << 2)) << 6) + o;
    #pragma unroll
    for (int r = 0; r < 4; ++r) {
      float v = acc[r] + bias;
      v = 0.5f * v * (1.0f + erff(v * 0.70710678118654752f));
      ob[r << 6] = f2bf(v);
    }
  }
}

// output: hidden = H @ o1^T (bf16 MFMA, K=64), bias+gelu, then o2 dot via
// per-lane scale + butterfly shfl_xor over the quad's 16 columns.
__global__ void __launch_bounds__(256) k_out(const unsigned short* __restrict__ hb,
                                             const unsigned short* __restrict__ o1wbf,
                                             const float* __restrict__ o1_b,
                                             const float* __restrict__ o2_w,
                                             const float* __restrict__ o2_b,
                                             float* __restrict__ out) {
  __shared__ unsigned short S[128 * 88];
  int t = threadIdx.x;
  long row = blockIdx.x >> 1;                  // (b,x) in [0,2048)
  int half = blockIdx.x & 1;
  const unsigned short* hbase = hb + (row << 14) + (half << 13);
  #pragma unroll
  for (int k = 0; k < 4; ++k) {
    int idx8 = t + (k << 8);
    short8 v = *(const short8*)(hbase + (idx8 << 3));
    int yy = idx8 >> 3, c8 = idx8 & 7;
    *(short8*)(&S[yy * 88 + (c8 << 3)]) = v;
  }
  int lane = t & 63;
  int kq = lane >> 4;
  int n = lane & 15;
  int wid = t >> 6;                            // rows [32*wid, 32*wid+32)
  const unsigned short* w0 = o1wbf + (n << 6) + (kq << 3);         // o = n
  const unsigned short* w1 = o1wbf + ((n + 16) << 6) + (kq << 3);  // o = n+16
  short8 B0a = *(const short8*)(w0);
  short8 B0b = *(const short8*)(w0 + 32);
  short8 B1a = *(const short8*)(w1);
  short8 B1b = *(const short8*)(w1 + 32);
  float b0 = o1_b[n], b1 = o1_b[n + 16];
  float g0 = o2_w[n], g1 = o2_w[n + 16];
  float ob2 = o2_b[0];
  __syncthreads();
  float* outp = out + row * 256 + (half << 7);
  #pragma unroll
  for (int mt = 0; mt < 2; ++mt) {
    int m0 = (wid << 5) + (mt << 4);
    const unsigned short* srow = &S[(m0 + n) * 88 + (kq << 3)];
    short8 a0 = *(const short8*)(srow);
    short8 a1 = *(const short8*)(srow + 32);
    f32x4 c0 = {0.0f, 0.0f, 0.0f, 0.0f}, c1 = {0.0f, 0.0f, 0.0f, 0.0f};
    c0 = __builtin_amdgcn_mfma_f32_16x16x32_bf16(a0, B0a, c0, 0, 0, 0);
    c0 = __builtin_amdgcn_mfma_f32_16x16x32_bf16(a1, B0b, c0, 0, 0, 0);
    c1 = __builtin_amdgcn_mfma_f32_16x16x32_bf16(a0, B1a, c1, 0, 0, 0);
    c1 = __builtin_amdgcn_mfma_f32_16x16x32_bf16(a1, B1b, c1, 0, 0, 0);
    #pragma unroll
    for (int r = 0; r < 4; ++r) {
      float v0 = c0[r] + b0;
      v0 = 0.5f * v0 * (1.0f + erff(v0 * 0.70710678118654752f));
      float v1 = c1[r] + b1;
      v1 = 0.5f * v1 * (1.0f + erff(v1 * 0.70710678118654752f));
      float s = v0 * g0 + v1 * g1;
      s += __shfl_xor(s, 1);
      s += __shfl_xor(s, 2);
      s += __shfl_xor(s, 4);
      s += __shfl_xor(s, 8);
      if (n == 0) outp[m0 + (kq << 2) + r] = s + ob2;
    }
  }
}

extern "C" void kernel_launch(void* const* d_in, const int* in_sizes, int n_in,
                              void* d_out, int out_size, void* d_ws, size_t ws_size,
                              hipStream_t stream) {
  const float* x       = (const float*)d_in[0];
  const float* in_w    = (const float*)d_in[1];
  const float* in_b    = (const float*)d_in[2];
  const float* spec_wr = (const float*)d_in[3];
  const float* spec_wi = (const float*)d_in[4];
  const float* pw_w    = (const float*)d_in[5];
  const float* pw_b    = (const float*)d_in[6];
  const float* o1_w    = (const float*)d_in[7];
  const float* o1_b    = (const float*)d_in[8];
  const float* o2_w    = (const float*)d_in[9];
  const float* o2_b    = (const float*)d_in[10];
  float* ws = (float*)d_ws;
  unsigned short* hb = (unsigned short*)(ws + OFF_H);
  float* Y      = ws + OFF_YA;
  unsigned short* A2 = (unsigned short*)(ws + OFF_YA);   // overlays Y (Y dead)
  float* Xf     = ws + OFF_XF;
  float* costab = ws + OFF_TAB;
  unsigned short* o1wbf = (unsigned short*)(ws + OFF_O1W);
  unsigned short* trig = (unsigned short*)(ws + OFF_TRIG);
  unsigned short* wt   = (unsigned short*)(ws + OFF_WT);
  unsigned short* trigT = (unsigned short*)(ws + OFF_TRIGT);
  float* out = (float*)d_out;

  k_init<<<73, 256, 0, stream>>>(ws, pw_w, o1_w);
  k_in<<<32768, 256, 0, stream>>>(x, in_w, in_b, hb);
  for (int l = 0; l < NLAYER; ++l) {
    k_f1<<<2048, 256, 0, stream>>>(hb, trigT, Y);
    k_f2<<<128, 256, 0, stream>>>(Y, costab, Xf);
    k_spec<<<512, 256, 0, stream>>>(Xf, spec_wr + (long)l * 1048576,
                                    spec_wi + (long)l * 1048576, costab, A2);
    k_pw<<<4096, 256, 0, stream>>>(hb, A2, wt + l * 4096, trig, pw_b + l * 64);
  }
  k_out<<<4096, 256, 0, stream>>>(hb, o1wbf, o1_b, o2_w, o2_b, out);
}

// Round 12
// 507.022 us; speedup vs baseline: 8.8494x; 1.2315x over previous
//
#include <hip/hip_runtime.h>
#include <math.h>

// FNO2d: B=8, CIN=2, COUT=1, W0=64, modes 16x16, NL=4, H=W=256
// h stored channels-last BF16: [B][H][W][64] ushort (consumers only ever use
// bf16(h) -> zero added error vs fp32 storage, half the traffic).
// Y  (F1 out, fp32): [B][H(x)][16ky][64c][2]
// Xf (F2 out, fp32): [B][64c][256m][2], m = kx*16+ky
// A2 (spec out, bf16): [B*256 rows][64o][32k']  k'<16: Ar*sc, k'>=16: -Ai*sc
// Trig  (bf16): [256y][32k'] (A-frags for k_pw I2)
// TrigT (bf16): [32 rows][256y] (A-frags for k_f1; rows 0-15 cos, 16-31 sin)
// k_f1 = bf16 MFMA GEMM: Y[ky][c] = TrigT @ H (K=256), fp32 accum.
// k_pw = bf16 MFMA GEMM: [H | Trig] @ [pw_w^T ; A2] + bias -> gelu.
// k_out = bf16 MFMA GEMM (H @ o1^T) + gelu + cross-lane o2 dot.
//
// HARD-WON RULES:
//  - (R2/R3/R5) NEVER use min-waves arg of __launch_bounds__ with per-thread
//    accumulator arrays: backend spills to hit the VGPR tier.
//  - (R4/R6/R9) per-thread accs + uniform weight streaming via s_load is
//    latency-bound; keep weights in VGPR MFMA B-frags.
//  - (R11) watch grid size vs 256 CUs: k_f2's 128-block grid left half the
//    chip idle and was pure latency (5% occupancy, 13% VALU).
//  - Spectral branch is ~500x smaller than pw branch at the output: bf16
//    everywhere in it costs ~1e-9 absmax (R7 calibration).

#define NLAYER 4

// ws offsets in floats
#define OFF_H     0L
#define OFF_YA    33554432L           // Y fp32 (4194304 fl) / A2 bf16 overlay
#define OFF_XF    37748736L           // 262144 fl
#define OFF_TAB   38010880L           // 256 fl
#define OFF_O1W   38011136L           // o1 bf16: 2048 ush = 1024 fl
#define OFF_TRIG  38013184L           // 8192 ush = 4096 fl
#define OFF_WT    38017280L           // 16384 ush = 8192 fl
#define OFF_TRIGT 38025472L           // 8192 ush = 4096 fl
#define WS_FLOATS 38029568L

typedef __attribute__((ext_vector_type(8))) short short8;
typedef __attribute__((ext_vector_type(4))) float f32x4;

__device__ __forceinline__ unsigned short f2bf(float f) {
  unsigned int u = __float_as_uint(f);
  u += 0x7FFF + ((u >> 16) & 1);          // round-to-nearest-even
  return (unsigned short)(u >> 16);
}

__global__ void k_init(float* __restrict__ ws, const float* __restrict__ pw_w,
                       const float* __restrict__ o1_w) {
  float* costab = ws + OFF_TAB;
  unsigned short* o1wbf = (unsigned short*)(ws + OFF_O1W);
  unsigned short* trig = (unsigned short*)(ws + OFF_TRIG);
  unsigned short* wt = (unsigned short*)(ws + OFF_WT);
  unsigned short* trigT = (unsigned short*)(ws + OFF_TRIGT);
  int t = blockIdx.x * blockDim.x + threadIdx.x;
  int stride = gridDim.x * blockDim.x;
  for (int m = t; m < 256; m += stride)
    costab[m] = (float)cos((double)m * (3.14159265358979323846 / 128.0));
  for (int idx = t; idx < 32 * 64; idx += stride)
    o1wbf[idx] = f2bf(o1_w[idx]);               // [o][c]
  for (int idx = t; idx < 256 * 32; idx += stride) {
    int y = idx >> 5, k = idx & 31;
    int mm = ((k & 15) * y) & 255;
    double ang = (double)mm * (3.14159265358979323846 / 128.0);
    double v = (k < 16) ? cos(ang) : sin(ang);
    trig[idx] = f2bf((float)v);
  }
  for (int idx = t; idx < 32 * 256; idx += stride) {   // trigT[r][y]
    int r = idx >> 8, y = idx & 255;
    int mm = ((r & 15) * y) & 255;
    double ang = (double)mm * (3.14159265358979323846 / 128.0);
    double v = (r < 16) ? cos(ang) : sin(ang);
    trigT[idx] = f2bf((float)v);
  }
  for (int idx = t; idx < NLAYER * 64 * 64; idx += stride)
    wt[idx] = f2bf(pw_w[idx]);                  // [l][o][c]
}

// input 1x1 conv: x [B][2][H][W] -> h bf16 [B][H][W][64]. 4 outputs/thread.
__global__ void __launch_bounds__(256) k_in(const float* __restrict__ x,
                                            const float* __restrict__ in_w,
                                            const float* __restrict__ in_b,
                                            unsigned short* __restrict__ hb) {
  long tid = (long)blockIdx.x * 256 + threadIdx.x;   // [0, 8*65536*16)
  int o0 = (int)(tid & 15) << 2;
  long p = tid >> 4;                                  // pixel index
  long b = p >> 16; long xy = p & 65535;
  float x0 = x[b * 131072 + xy];
  float x1 = x[b * 131072 + 65536 + xy];
  ushort4 r;
  r.x = f2bf(in_b[o0]     + in_w[o0 * 2]     * x0 + in_w[o0 * 2 + 1] * x1);
  r.y = f2bf(in_b[o0 + 1] + in_w[o0 * 2 + 2] * x0 + in_w[o0 * 2 + 3] * x1);
  r.z = f2bf(in_b[o0 + 2] + in_w[o0 * 2 + 4] * x0 + in_w[o0 * 2 + 5] * x1);
  r.w = f2bf(in_b[o0 + 3] + in_w[o0 * 2 + 6] * x0 + in_w[o0 * 2 + 7] * x1);
  *(ushort4*)(hb + (p << 6) + o0) = r;
}

// F1 as bf16 MFMA GEMM. Block = one (b,x) row. Y[ky][c] = sum_y T[ky][y] h[y][c].
// St[c][y] transposed, swizzled: element (c,y) at c*256 + ((yb^(c>>3))&31)*8 + (y&7),
// yb = y>>3. Keeps ds_read_b128 16B-aligned, <=2-way banks both directions.
// M=32 (rows 0-15 cos -> Yr, 16-31 sin -> -Yi), N=64, K=256. 4 waves x 2 (mt,nt)
// pairs x 8 K-steps. Epilogue: D row = ky (quad*4+r), col = c; scale 1/16.
__global__ void __launch_bounds__(256) k_f1(const unsigned short* __restrict__ hb,
                                            const unsigned short* __restrict__ trigT,
                                            float* __restrict__ Y) {
  __shared__ unsigned short St[64 * 256];
  int t = threadIdx.x;
  long row = blockIdx.x;
  const unsigned short* hrow = hb + (row << 14);
  #pragma unroll
  for (int kk = 0; kk < 8; ++kk) {
    int idx8 = t + (kk << 8);                  // [0,2048) ushort8 chunks
    short8 v = *(const short8*)(hrow + (idx8 << 3));
    int y = idx8 >> 3, c0 = (idx8 & 7) << 3;
    int yb = y >> 3, y7 = y & 7;
    #pragma unroll
    for (int e = 0; e < 8; ++e) {
      int c = c0 + e;
      St[(c << 8) + (((yb ^ (c >> 3)) & 31) << 3) + y7] = (unsigned short)v[e];
    }
  }
  __syncthreads();
  int lane = t & 63;
  int wid = t >> 6;
  int kq = lane >> 4, n = lane & 15;
  #pragma unroll
  for (int pp = 0; pp < 2; ++pp) {
    int p = wid + (pp << 2);
    int mt = p & 1, nt = p >> 1;               // mt: 0=cos/Yr, 1=sin/Yi
    int trow = (mt << 4) + n;                  // A: m = lane&15
    int c = (nt << 4) + n;                     // B: n = lane&15
    const unsigned short* abase = trigT + (trow << 8) + (kq << 3);
    f32x4 acc = {0.0f, 0.0f, 0.0f, 0.0f};
    #pragma unroll
    for (int k0 = 0; k0 < 8; ++k0) {
      short8 af = *(const short8*)(abase + (k0 << 5));
      int yb = (k0 << 2) + kq;
      short8 bf = *(const short8*)(&St[(c << 8) + (((yb ^ (c >> 3)) & 31) << 3)]);
      acc = __builtin_amdgcn_mfma_f32_16x16x32_bf16(af, bf, acc, 0, 0, 0);
    }
    float sgn = mt ? -0.0625f : 0.0625f;       // Yi = -sum sin * h / 16
    float* yp = Y + (row << 11) + (kq << 9) + (c << 1) + mt;
    #pragma unroll
    for (int r = 0; r < 4; ++r)
      yp[r << 7] = acc[r] * sgn;               // ky = kq*4 + r
  }
}

// F2 v2 (R11): partial DFT along x. grid = (b,ky,cq) [512 blocks] -- was 128,
// which left half the CUs idle (5% occupancy, pure latency). thread =
// (c16 = t&15, kx = t>>4), ONE kx per thread, 2 accs; lanes 0-15 load 128 B
// contiguous, other kx groups repeat the same addresses (TA broadcast).
// unroll 4 keeps 4 strided loads in flight. Same fp32 math as before.
__global__ void __launch_bounds__(256) k_f2(const float* __restrict__ Y,
                                            const float* __restrict__ costab,
                                            float* __restrict__ Xf) {
  __shared__ float T[256];
  int t = threadIdx.x;
  T[t] = costab[t];
  __syncthreads();
  int bk = blockIdx.x >> 2;            // b*16 + ky
  int b = bk >> 4, ky = bk & 15;
  int c = ((blockIdx.x & 3) << 4) + (t & 15);
  int kx = t >> 4;
  const float* ybase = Y + ((long)b * 4096 + ky) * 128 + c * 2;
  float ar = 0.0f, ai = 0.0f;
  int m = 0;
  #pragma unroll 4
  for (int x = 0; x < 256; ++x) {
    float2 v = *(const float2*)(ybase + (long)x * 2048);
    float cv = T[m], sv = T[(m + 192) & 255];
    ar += v.x * cv + v.y * sv;         // (yr + i yi)(c - i s)
    ai += v.y * cv - v.x * sv;
    m = (m + kx) & 255;
  }
  float* o = Xf + ((long)b * 64 + c) * 512 + (kx * 16 + ky) * 2;
  o[0] = ar * 0.0625f;
  o[1] = ai * 0.0625f;
}

// mode GEMM + I1. block = b*64+o [512]. phase1: thread=mode m; phase2: thread=x.
// Output: A2 bf16 [row][o][32k'], k'<16: Ar*sc, k'>=16: -Ai*sc
// (sc = 1/256 for ky=0 else 1/128; I1 1/16 * I2 1/16 * posfreq 2).
__global__ void __launch_bounds__(256) k_spec(const float* __restrict__ Xf,
                                              const float* __restrict__ wr,
                                              const float* __restrict__ wi,
                                              const float* __restrict__ costab,
                                              unsigned short* __restrict__ A2) {
  __shared__ float T[256];
  __shared__ float Gr[256], Gi[256];
  int t = threadIdx.x;
  T[t] = costab[t];
  int b = blockIdx.x >> 6, o = blockIdx.x & 63;
  {
    int m = t;
    float gr = 0, gi = 0;
    const float* xb = Xf + (long)b * 32768 + m * 2;
    const float* wrb = wr + (long)o * 256 + m;    // [i][o][m]
    const float* wib = wi + (long)o * 256 + m;
    for (int i = 0; i < 64; ++i) {
      float xr = xb[(long)i * 512], xi = xb[(long)i * 512 + 1];
      float wrv = wrb[(long)i * 16384], wiv = wib[(long)i * 16384];
      gr += xr * wrv - xi * wiv;
      gi += xr * wiv + xi * wrv;
    }
    Gr[m] = gr; Gi[m] = gi;
  }
  __syncthreads();
  int x = t;
  float ar[16], ai[16];
  #pragma unroll
  for (int ky = 0; ky < 16; ++ky) { ar[ky] = 0.0f; ai[ky] = 0.0f; }
  for (int kx = 0; kx < 16; ++kx) {
    int mm = (kx * x) & 255;
    float cv = T[mm], sv = T[(mm + 192) & 255];
    #pragma unroll
    for (int ky = 0; ky < 16; ++ky) {
      float gr = Gr[kx * 16 + ky], gi = Gi[kx * 16 + ky];
      ar[ky] += gr * cv - gi * sv;     // (gr+i gi)(c + i s)
      ai[ky] += gr * sv + gi * cv;
    }
  }
  unsigned short* ab = A2 + ((long)(b * 256 + x) << 11) + (o << 5);
  #pragma unroll
  for (int ky = 0; ky < 16; ++ky) {
    float sc = (ky == 0) ? 0.00390625f : 0.0078125f;   // 1/256, 1/128 exact
    ab[ky] = f2bf(ar[ky] * sc);
    ab[16 + ky] = f2bf(-ai[ky] * sc);
  }
}

// I2 + pointwise conv + GELU, in place on bf16 h — MFMA version.
// Block = half an (b,x) row (128 y), 4 waves; wave w owns o-strip [16w,16w+16).
// S stride 88 shorts (22 dwords, gcd 2 with 32 -> 2-way banks, free).
__global__ void __launch_bounds__(256) k_pw(unsigned short* __restrict__ hb,
                                            const unsigned short* __restrict__ A2,
                                            const unsigned short* __restrict__ Wt,
                                            const unsigned short* __restrict__ trig,
                                            const float* __restrict__ pw_b) {
  __shared__ unsigned short S[128 * 88];
  int t = threadIdx.x;
  long row = blockIdx.x >> 1;                  // (b,x) in [0,2048)
  int half = blockIdx.x & 1;                   // y half
  const unsigned short* hbase = hb + (row << 14) + (half << 13);
  #pragma unroll
  for (int k = 0; k < 4; ++k) {
    int idx8 = t + (k << 8);                   // [0,1024) ushort8 chunks
    short8 v = *(const short8*)(hbase + (idx8 << 3));
    int yy = idx8 >> 3, c8 = idx8 & 7;
    *(short8*)(&S[yy * 88 + (c8 << 3)]) = v;
  }
  int lane = t & 63;
  int kq = lane >> 4;                          // k-quad
  int n = lane & 15;
  int o = ((t >> 6) << 4) + n;                 // wave o-strip + n
  const unsigned short* wrow = Wt + (o << 6) + (kq << 3);
  short8 B0 = *(const short8*)(wrow);                               // c 0..31
  short8 B1 = *(const short8*)(wrow + 32);                          // c 32..63
  short8 B2 = *(const short8*)(A2 + (row << 11) + (o << 5) + (kq << 3)); // k'
  float bias = pw_b[o];
  __syncthreads();                             // S staged; h reads done
  #pragma unroll 2
  for (int m0 = 0; m0 < 128; m0 += 16) {
    const unsigned short* srow = &S[(m0 + n) * 88 + (kq << 3)];
    short8 a0 = *(const short8*)(srow);
    short8 a1 = *(const short8*)(srow + 32);
    short8 a2 = *(const short8*)(trig + (((half << 7) + m0 + n) << 5) + (kq << 3));
    f32x4 acc = {0.0f, 0.0f, 0.0f, 0.0f};
    acc = __builtin_amdgcn_mfma_f32_16x16x32_bf16(a0, B0, acc, 0, 0, 0);
    acc = __builtin_amdgcn_mfma_f32_16x16x32_bf16(a1, B1, acc, 0, 0, 0);
    acc = __builtin_amdgcn_mfma_f32_16x16x32_bf16(a2, B2, acc, 0, 0, 0);
    unsigned short* ob = hb + (row << 14) + (((half << 7) + m0 + (kq << 2)) << 6) + o;
    #pragma unroll
    for (int r = 0; r < 4; ++r) {
      float v = acc[r] + bias;
      v = 0.5f * v * (1.0f + erff(v * 0.70710678118654752f));
      ob[r << 6] = f2bf(v);
    }
  }
}

// output: hidden = H @ o1^T (bf16 MFMA, K=64), bias+gelu, then o2 dot via
// per-lane scale + butterfly shfl_xor over the quad's 16 columns.
__global__ void __launch_bounds__(256) k_out(const unsigned short* __restrict__ hb,
                                             const unsigned short* __restrict__ o1wbf,
                                             const float* __restrict__ o1_b,
                                             const float* __restrict__ o2_w,
                                             const float* __restrict__ o2_b,
                                             float* __restrict__ out) {
  __shared__ unsigned short S[128 * 88];
  int t = threadIdx.x;
  long row = blockIdx.x >> 1;                  // (b,x) in [0,2048)
  int half = blockIdx.x & 1;
  const unsigned short* hbase = hb + (row << 14) + (half << 13);
  #pragma unroll
  for (int k = 0; k < 4; ++k) {
    int idx8 = t + (k << 8);
    short8 v = *(const short8*)(hbase + (idx8 << 3));
    int yy = idx8 >> 3, c8 = idx8 & 7;
    *(short8*)(&S[yy * 88 + (c8 << 3)]) = v;
  }
  int lane = t & 63;
  int kq = lane >> 4;
  int n = lane & 15;
  int wid = t >> 6;                            // rows [32*wid, 32*wid+32)
  const unsigned short* w0 = o1wbf + (n << 6) + (kq << 3);         // o = n
  const unsigned short* w1 = o1wbf + ((n + 16) << 6) + (kq << 3);  // o = n+16
  short8 B0a = *(const short8*)(w0);
  short8 B0b = *(const short8*)(w0 + 32);
  short8 B1a = *(const short8*)(w1);
  short8 B1b = *(const short8*)(w1 + 32);
  float b0 = o1_b[n], b1 = o1_b[n + 16];
  float g0 = o2_w[n], g1 = o2_w[n + 16];
  float ob2 = o2_b[0];
  __syncthreads();
  float* outp = out + row * 256 + (half << 7);
  #pragma unroll
  for (int mt = 0; mt < 2; ++mt) {
    int m0 = (wid << 5) + (mt << 4);
    const unsigned short* srow = &S[(m0 + n) * 88 + (kq << 3)];
    short8 a0 = *(const short8*)(srow);
    short8 a1 = *(const short8*)(srow + 32);
    f32x4 c0 = {0.0f, 0.0f, 0.0f, 0.0f}, c1 = {0.0f, 0.0f, 0.0f, 0.0f};
    c0 = __builtin_amdgcn_mfma_f32_16x16x32_bf16(a0, B0a, c0, 0, 0, 0);
    c0 = __builtin_amdgcn_mfma_f32_16x16x32_bf16(a1, B0b, c0, 0, 0, 0);
    c1 = __builtin_amdgcn_mfma_f32_16x16x32_bf16(a0, B1a, c1, 0, 0, 0);
    c1 = __builtin_amdgcn_mfma_f32_16x16x32_bf16(a1, B1b, c1, 0, 0, 0);
    #pragma unroll
    for (int r = 0; r < 4; ++r) {
      float v0 = c0[r] + b0;
      v0 = 0.5f * v0 * (1.0f + erff(v0 * 0.70710678118654752f));
      float v1 = c1[r] + b1;
      v1 = 0.5f * v1 * (1.0f + erff(v1 * 0.70710678118654752f));
      float s = v0 * g0 + v1 * g1;
      s += __shfl_xor(s, 1);
      s += __shfl_xor(s, 2);
      s += __shfl_xor(s, 4);
      s += __shfl_xor(s, 8);
      if (n == 0) outp[m0 + (kq << 2) + r] = s + ob2;
    }
  }
}

extern "C" void kernel_launch(void* const* d_in, const int* in_sizes, int n_in,
                              void* d_out, int out_size, void* d_ws, size_t ws_size,
                              hipStream_t stream) {
  const float* x       = (const float*)d_in[0];
  const float* in_w    = (const float*)d_in[1];
  const float* in_b    = (const float*)d_in[2];
  const float* spec_wr = (const float*)d_in[3];
  const float* spec_wi = (const float*)d_in[4];
  const float* pw_w    = (const float*)d_in[5];
  const float* pw_b    = (const float*)d_in[6];
  const float* o1_w    = (const float*)d_in[7];
  const float* o1_b    = (const float*)d_in[8];
  const float* o2_w    = (const float*)d_in[9];
  const float* o2_b    = (const float*)d_in[10];
  float* ws = (float*)d_ws;
  unsigned short* hb = (unsigned short*)(ws + OFF_H);
  float* Y      = ws + OFF_YA;
  unsigned short* A2 = (unsigned short*)(ws + OFF_YA);   // overlays Y (Y dead)
  float* Xf     = ws + OFF_XF;
  float* costab = ws + OFF_TAB;
  unsigned short* o1wbf = (unsigned short*)(ws + OFF_O1W);
  unsigned short* trig = (unsigned short*)(ws + OFF_TRIG);
  unsigned short* wt   = (unsigned short*)(ws + OFF_WT);
  unsigned short* trigT = (unsigned short*)(ws + OFF_TRIGT);
  float* out = (float*)d_out;

  k_init<<<73, 256, 0, stream>>>(ws, pw_w, o1_w);
  k_in<<<32768, 256, 0, stream>>>(x, in_w, in_b, hb);
  for (int l = 0; l < NLAYER; ++l) {
    k_f1<<<2048, 256, 0, stream>>>(hb, trigT, Y);
    k_f2<<<512, 256, 0, stream>>>(Y, costab, Xf);
    k_spec<<<512, 256, 0, stream>>>(Xf, spec_wr + (long)l * 1048576,
                                    spec_wi + (long)l * 1048576, costab, A2);
    k_pw<<<4096, 256, 0, stream>>>(hb, A2, wt + l * 4096, trig, pw_b + l * 64);
  }
  k_out<<<4096, 256, 0, stream>>>(hb, o1wbf, o1_b, o2_w, o2_b, out);
}

// Round 14
// 496.796 us; speedup vs baseline: 9.0315x; 1.0206x over previous
//
#include <hip/hip_runtime.h>
#include <math.h>

// FNO2d: B=8, CIN=2, COUT=1, W0=64, modes 16x16, NL=4, H=W=256
// h stored channels-last BF16: [B][H][W][64] ushort.
// Y  (F1 out, fp32): [B][H(x)][16ky][64c][2]
// Xf (F2 out, fp32): [B][64c][256m][2], m = kx*16+ky
// A2 (spec out, bf16): [B*256 rows][64o][32k'] -- separate region; must not
//    overlay Y (fused k_pw writes Y while other blocks still read A2).
// Trig  (bf16): [256y][32k'] (A-frags for k_pw I2)
// TrigT (bf16): [32 rows][256y] (A-frags for F1; rows 0-15 cos, 16-31 sin)
// k_f1 (layer 0 only) = bf16 MFMA GEMM: Y = TrigT @ H (K=256), fp32 accum.
// k_pw = bf16 MFMA GEMM [H | Trig] @ [pw_w^T ; A2] + bias -> gelu -> hb,
//        FUSED with next layer's F1 via LDS (stage -> pw -> re-stage -> F1,
//        barrier-separated; R13's race was reading global h while writing it).
// k_out = bf16 MFMA GEMM (H @ o1^T) + gelu + cross-lane o2 dot.
//
// HARD-WON RULES:
//  - (R2/R3/R5) NEVER use min-waves arg of __launch_bounds__ with per-thread
//    accumulator arrays: backend spills to hit the VGPR tier.
//  - (R4/R6/R9) per-thread accs + uniform weight streaming via s_load is
//    latency-bound; keep weights in VGPR MFMA B-frags.
//  - (R11) grid must cover 256 CUs.  (R12) fuse pairs sharing a row tile.
//  - (R13) in-place kernels must stage the ENTIRE input tile to LDS behind a
//    barrier before the first in-place write -- no direct global reads.

#define NLAYER 4

// ws offsets in floats
#define OFF_H     0L                  // hb ushorts, floats [0, 8.4M)
#define OFF_A2    16777216L           // A2 bf16: 4.2M ush = 2.1M fl
#define OFF_YA    33554432L           // Y fp32 (4194304 fl)
#define OFF_XF    37748736L           // 262144 fl
#define OFF_TAB   38010880L           // 256 fl
#define OFF_O1W   38011136L           // o1 bf16: 2048 ush = 1024 fl
#define OFF_TRIG  38013184L           // 8192 ush = 4096 fl
#define OFF_WT    38017280L           // 16384 ush = 8192 fl
#define OFF_TRIGT 38025472L           // 8192 ush = 4096 fl
#define WS_FLOATS 38029568L

typedef __attribute__((ext_vector_type(8))) short short8;
typedef __attribute__((ext_vector_type(4))) float f32x4;

__device__ __forceinline__ unsigned short f2bf(float f) {
  unsigned int u = __float_as_uint(f);
  u += 0x7FFF + ((u >> 16) & 1);          // round-to-nearest-even
  return (unsigned short)(u >> 16);
}

__global__ void k_init(float* __restrict__ ws, const float* __restrict__ pw_w,
                       const float* __restrict__ o1_w) {
  float* costab = ws + OFF_TAB;
  unsigned short* o1wbf = (unsigned short*)(ws + OFF_O1W);
  unsigned short* trig = (unsigned short*)(ws + OFF_TRIG);
  unsigned short* wt = (unsigned short*)(ws + OFF_WT);
  unsigned short* trigT = (unsigned short*)(ws + OFF_TRIGT);
  int t = blockIdx.x * blockDim.x + threadIdx.x;
  int stride = gridDim.x * blockDim.x;
  for (int m = t; m < 256; m += stride)
    costab[m] = (float)cos((double)m * (3.14159265358979323846 / 128.0));
  for (int idx = t; idx < 32 * 64; idx += stride)
    o1wbf[idx] = f2bf(o1_w[idx]);               // [o][c]
  for (int idx = t; idx < 256 * 32; idx += stride) {
    int y = idx >> 5, k = idx & 31;
    int mm = ((k & 15) * y) & 255;
    double ang = (double)mm * (3.14159265358979323846 / 128.0);
    double v = (k < 16) ? cos(ang) : sin(ang);
    trig[idx] = f2bf((float)v);
  }
  for (int idx = t; idx < 32 * 256; idx += stride) {   // trigT[r][y]
    int r = idx >> 8, y = idx & 255;
    int mm = ((r & 15) * y) & 255;
    double ang = (double)mm * (3.14159265358979323846 / 128.0);
    double v = (r < 16) ? cos(ang) : sin(ang);
    trigT[idx] = f2bf((float)v);
  }
  for (int idx = t; idx < NLAYER * 64 * 64; idx += stride)
    wt[idx] = f2bf(pw_w[idx]);                  // [l][o][c]
}

// input 1x1 conv: x [B][2][H][W] -> h bf16 [B][H][W][64]. 4 outputs/thread.
__global__ void __launch_bounds__(256) k_in(const float* __restrict__ x,
                                            const float* __restrict__ in_w,
                                            const float* __restrict__ in_b,
                                            unsigned short* __restrict__ hb) {
  long tid = (long)blockIdx.x * 256 + threadIdx.x;   // [0, 8*65536*16)
  int o0 = (int)(tid & 15) << 2;
  long p = tid >> 4;                                  // pixel index
  long b = p >> 16; long xy = p & 65535;
  float x0 = x[b * 131072 + xy];
  float x1 = x[b * 131072 + 65536 + xy];
  ushort4 r;
  r.x = f2bf(in_b[o0]     + in_w[o0 * 2]     * x0 + in_w[o0 * 2 + 1] * x1);
  r.y = f2bf(in_b[o0 + 1] + in_w[o0 * 2 + 2] * x0 + in_w[o0 * 2 + 3] * x1);
  r.z = f2bf(in_b[o0 + 2] + in_w[o0 * 2 + 4] * x0 + in_w[o0 * 2 + 5] * x1);
  r.w = f2bf(in_b[o0 + 3] + in_w[o0 * 2 + 6] * x0 + in_w[o0 * 2 + 7] * x1);
  *(ushort4*)(hb + (p << 6) + o0) = r;
}

// F1 standalone (layer 0 only). Block = one (b,x) row.
__global__ void __launch_bounds__(256) k_f1(const unsigned short* __restrict__ hb,
                                            const unsigned short* __restrict__ trigT,
                                            float* __restrict__ Y) {
  __shared__ unsigned short St[64 * 256];
  int t = threadIdx.x;
  long row = blockIdx.x;
  const unsigned short* hrow = hb + (row << 14);
  #pragma unroll
  for (int kk = 0; kk < 8; ++kk) {
    int idx8 = t + (kk << 8);                  // [0,2048) ushort8 chunks
    short8 v = *(const short8*)(hrow + (idx8 << 3));
    int y = idx8 >> 3, c0 = (idx8 & 7) << 3;
    int yb = y >> 3, y7 = y & 7;
    #pragma unroll
    for (int e = 0; e < 8; ++e) {
      int c = c0 + e;
      St[(c << 8) + (((yb ^ (c >> 3)) & 31) << 3) + y7] = (unsigned short)v[e];
    }
  }
  __syncthreads();
  int lane = t & 63;
  int wid = t >> 6;
  int kq = lane >> 4, n = lane & 15;
  #pragma unroll
  for (int pp = 0; pp < 2; ++pp) {
    int p = wid + (pp << 2);
    int mt = p & 1, nt = p >> 1;               // mt: 0=cos/Yr, 1=sin/Yi
    int trow = (mt << 4) + n;                  // A: m = lane&15
    int c = (nt << 4) + n;                     // B: n = lane&15
    const unsigned short* abase = trigT + (trow << 8) + (kq << 3);
    f32x4 acc = {0.0f, 0.0f, 0.0f, 0.0f};
    #pragma unroll
    for (int k0 = 0; k0 < 8; ++k0) {
      short8 af = *(const short8*)(abase + (k0 << 5));
      int yb = (k0 << 2) + kq;
      short8 bf = *(const short8*)(&St[(c << 8) + (((yb ^ (c >> 3)) & 31) << 3)]);
      acc = __builtin_amdgcn_mfma_f32_16x16x32_bf16(af, bf, acc, 0, 0, 0);
    }
    float sgn = mt ? -0.0625f : 0.0625f;       // Yi = -sum sin * h / 16
    float* yp = Y + (row << 11) + (kq << 9) + (c << 1) + mt;
    #pragma unroll
    for (int r = 0; r < 4; ++r)
      yp[r << 7] = acc[r] * sgn;               // ky = kq*4 + r
  }
}

// F2 (R11 shape): grid = (b,ky,cq) [512 blocks], thread = (c16, kx).
__global__ void __launch_bounds__(256) k_f2(const float* __restrict__ Y,
                                            const float* __restrict__ costab,
                                            float* __restrict__ Xf) {
  __shared__ float T[256];
  int t = threadIdx.x;
  T[t] = costab[t];
  __syncthreads();
  int bk = blockIdx.x >> 2;            // b*16 + ky
  int b = bk >> 4, ky = bk & 15;
  int c = ((blockIdx.x & 3) << 4) + (t & 15);
  int kx = t >> 4;
  const float* ybase = Y + ((long)b * 4096 + ky) * 128 + c * 2;
  float ar = 0.0f, ai = 0.0f;
  int m = 0;
  #pragma unroll 4
  for (int x = 0; x < 256; ++x) {
    float2 v = *(const float2*)(ybase + (long)x * 2048);
    float cv = T[m], sv = T[(m + 192) & 255];
    ar += v.x * cv + v.y * sv;         // (yr + i yi)(c - i s)
    ai += v.y * cv - v.x * sv;
    m = (m + kx) & 255;
  }
  float* o = Xf + ((long)b * 64 + c) * 512 + (kx * 16 + ky) * 2;
  o[0] = ar * 0.0625f;
  o[1] = ai * 0.0625f;
}

// mode GEMM + I1. block = b*64+o [512]. Output A2 bf16 [row][o][32k'].
__global__ void __launch_bounds__(256) k_spec(const float* __restrict__ Xf,
                                              const float* __restrict__ wr,
                                              const float* __restrict__ wi,
                                              const float* __restrict__ costab,
                                              unsigned short* __restrict__ A2) {
  __shared__ float T[256];
  __shared__ float Gr[256], Gi[256];
  int t = threadIdx.x;
  T[t] = costab[t];
  int b = blockIdx.x >> 6, o = blockIdx.x & 63;
  {
    int m = t;
    float gr = 0, gi = 0;
    const float* xb = Xf + (long)b * 32768 + m * 2;
    const float* wrb = wr + (long)o * 256 + m;    // [i][o][m]
    const float* wib = wi + (long)o * 256 + m;
    for (int i = 0; i < 64; ++i) {
      float xr = xb[(long)i * 512], xi = xb[(long)i * 512 + 1];
      float wrv = wrb[(long)i * 16384], wiv = wib[(long)i * 16384];
      gr += xr * wrv - xi * wiv;
      gi += xr * wiv + xi * wrv;
    }
    Gr[m] = gr; Gi[m] = gi;
  }
  __syncthreads();
  int x = t;
  float ar[16], ai[16];
  #pragma unroll
  for (int ky = 0; ky < 16; ++ky) { ar[ky] = 0.0f; ai[ky] = 0.0f; }
  for (int kx = 0; kx < 16; ++kx) {
    int mm = (kx * x) & 255;
    float cv = T[mm], sv = T[(mm + 192) & 255];
    #pragma unroll
    for (int ky = 0; ky < 16; ++ky) {
      float gr = Gr[kx * 16 + ky], gi = Gi[kx * 16 + ky];
      ar[ky] += gr * cv - gi * sv;     // (gr+i gi)(c + i s)
      ai[ky] += gr * sv + gi * cv;
    }
  }
  unsigned short* ab = A2 + ((long)(b * 256 + x) << 11) + (o << 5);
  #pragma unroll
  for (int ky = 0; ky < 16; ++ky) {
    float sc = (ky == 0) ? 0.00390625f : 0.0078125f;   // 1/256, 1/128 exact
    ab[ky] = f2bf(ar[ky] * sc);
    ab[16 + ky] = f2bf(-ai[ky] * sc);
  }
}

// I2 + pointwise conv + GELU (in place on hb) FUSED with next layer's F1.
// Block = one full (b,x) row, 512 threads = 8 waves.
// Phase 0: stage 256x64 h tile -> S (stride 88, R12-proven), barrier.
// Phase 1: wave w = (y-half w>>2, o-strip (w&3)*16); A-frags from S; gelu ->
//          global hb + 8 ushort4 registers.
// Phase 2 (do_f1): barrier (S reads drained), write reg tile into S in F1
//          B-layout (k_f1 swizzle (yb^(c>>3))&31), barrier, F1 MFMA -> Y.
// Bit-identical math to the R12 split kernels.
__global__ void __launch_bounds__(512) k_pw(unsigned short* __restrict__ hb,
                                            const unsigned short* __restrict__ A2,
                                            const unsigned short* __restrict__ Wt,
                                            const unsigned short* __restrict__ trig,
                                            const unsigned short* __restrict__ trigT,
                                            const float* __restrict__ pw_b,
                                            float* __restrict__ Y,
                                            int do_f1) {
  __shared__ unsigned short S[256 * 88];       // 44 KB; F1 B-tile (32 KB) reuses it
  int t = threadIdx.x;
  long row = blockIdx.x;                       // (b,x) in [0,2048)
  int lane = t & 63;
  int wid = t >> 6;                            // 0..7
  int kq = lane >> 4, n = lane & 15;
  int half = wid >> 2;
  int o = ((wid & 3) << 4) + n;
  const unsigned short* wrow = Wt + (o << 6) + (kq << 3);
  short8 B0 = *(const short8*)(wrow);                               // c 0..31
  short8 B1 = *(const short8*)(wrow + 32);                          // c 32..63
  short8 B2 = *(const short8*)(A2 + (row << 11) + (o << 5) + (kq << 3)); // k'
  float bias = pw_b[o];
  // ---- phase 0: stage the whole row tile (256y x 64c) ----
  const unsigned short* hrow = hb + (row << 14);
  #pragma unroll
  for (int k = 0; k < 4; ++k) {
    int idx8 = t + (k << 9);                   // [0,2048) ushort8 chunks
    short8 v = *(const short8*)(hrow + (idx8 << 3));
    int yy = idx8 >> 3, c8 = idx8 & 7;
    *(short8*)(&S[yy * 88 + (c8 << 3)]) = v;
  }
  __syncthreads();                             // staging done before in-place writes
  // ---- phase 1: pw GEMM + gelu ----
  ushort4 res[8];
  #pragma unroll
  for (int i = 0; i < 8; ++i) {
    int m0 = i << 4;
    int yrow = (half << 7) + m0 + n;
    const unsigned short* srow = &S[yrow * 88 + (kq << 3)];
    short8 a0 = *(const short8*)(srow);
    short8 a1 = *(const short8*)(srow + 32);
    short8 a2 = *(const short8*)(trig + (yrow << 5) + (kq << 3));
    f32x4 acc = {0.0f, 0.0f, 0.0f, 0.0f};
    acc = __builtin_amdgcn_mfma_f32_16x16x32_bf16(a0, B0, acc, 0, 0, 0);
    acc = __builtin_amdgcn_mfma_f32_16x16x32_bf16(a1, B1, acc, 0, 0, 0);
    acc = __builtin_amdgcn_mfma_f32_16x16x32_bf16(a2, B2, acc, 0, 0, 0);
    float v0 = acc[0] + bias;
    v0 = 0.5f * v0 * (1.0f + erff(v0 * 0.70710678118654752f));
    float v1 = acc[1] + bias;
    v1 = 0.5f * v1 * (1.0f + erff(v1 * 0.70710678118654752f));
    float v2 = acc[2] + bias;
    v2 = 0.5f * v2 * (1.0f + erff(v2 * 0.70710678118654752f));
    float v3 = acc[3] + bias;
    v3 = 0.5f * v3 * (1.0f + erff(v3 * 0.70710678118654752f));
    res[i].x = f2bf(v0); res[i].y = f2bf(v1);
    res[i].z = f2bf(v2); res[i].w = f2bf(v3);
    int y0 = (half << 7) + m0 + (kq << 2);     // rows y0..y0+3, col o
    unsigned short* ob = hb + (row << 14) + ((long)y0 << 6) + o;
    ob[0] = res[i].x; ob[64] = res[i].y; ob[128] = res[i].z; ob[192] = res[i].w;
  }
  if (do_f1) {
    __syncthreads();                           // all phase-1 S reads drained
    // ---- phase 2a: re-stage gelu tile into S in F1 B-layout ----
    #pragma unroll
    for (int i = 0; i < 8; ++i) {
      int y0 = (half << 7) + (i << 4) + (kq << 2);
      int yb = y0 >> 3;
      *(ushort4*)(&S[(o << 8) + (((yb ^ (o >> 3)) & 31) << 3) + (y0 & 7)]) = res[i];
    }
    __syncthreads();
    // ---- phase 2b: F1 MFMA -> Y ----
    int mt = wid & 1, nt = wid >> 1;           // 8 waves = 2 mt x 4 nt
    int trow = (mt << 4) + n;
    int c = (nt << 4) + n;
    const unsigned short* abase = trigT + (trow << 8) + (kq << 3);
    f32x4 acc = {0.0f, 0.0f, 0.0f, 0.0f};
    #pragma unroll
    for (int k0 = 0; k0 < 8; ++k0) {
      short8 af = *(const short8*)(abase + (k0 << 5));
      int yb = (k0 << 2) + kq;
      short8 bf = *(const short8*)(&S[(c << 8) + (((yb ^ (c >> 3)) & 31) << 3)]);
      acc = __builtin_amdgcn_mfma_f32_16x16x32_bf16(af, bf, acc, 0, 0, 0);
    }
    float sgn = mt ? -0.0625f : 0.0625f;
    float* yp = Y + (row << 11) + (kq << 9) + (c << 1) + mt;
    #pragma unroll
    for (int r = 0; r < 4; ++r)
      yp[r << 7] = acc[r] * sgn;               // ky = kq*4 + r
  }
}

// output: hidden = H @ o1^T (bf16 MFMA, K=64), bias+gelu, then o2 dot via
// per-lane scale + butterfly shfl_xor over the quad's 16 columns.
__global__ void __launch_bounds__(256) k_out(const unsigned short* __restrict__ hb,
                                             const unsigned short* __restrict__ o1wbf,
                                             const float* __restrict__ o1_b,
                                             const float* __restrict__ o2_w,
                                             const float* __restrict__ o2_b,
                                             float* __restrict__ out) {
  __shared__ unsigned short S[128 * 88];
  int t = threadIdx.x;
  long row = blockIdx.x >> 1;                  // (b,x) in [0,2048)
  int half = blockIdx.x & 1;
  const unsigned short* hbase = hb + (row << 14) + (half << 13);
  #pragma unroll
  for (int k = 0; k < 4; ++k) {
    int idx8 = t + (k << 8);
    short8 v = *(const short8*)(hbase + (idx8 << 3));
    int yy = idx8 >> 3, c8 = idx8 & 7;
    *(short8*)(&S[yy * 88 + (c8 << 3)]) = v;
  }
  int lane = t & 63;
  int kq = lane >> 4;
  int n = lane & 15;
  int wid = t >> 6;                            // rows [32*wid, 32*wid+32)
  const unsigned short* w0 = o1wbf + (n << 6) + (kq << 3);         // o = n
  const unsigned short* w1 = o1wbf + ((n + 16) << 6) + (kq << 3);  // o = n+16
  short8 B0a = *(const short8*)(w0);
  short8 B0b = *(const short8*)(w0 + 32);
  short8 B1a = *(const short8*)(w1);
  short8 B1b = *(const short8*)(w1 + 32);
  float b0 = o1_b[n], b1 = o1_b[n + 16];
  float g0 = o2_w[n], g1 = o2_w[n + 16];
  float ob2 = o2_b[0];
  __syncthreads();
  float* outp = out + row * 256 + (half << 7);
  #pragma unroll
  for (int mt = 0; mt < 2; ++mt) {
    int m0 = (wid << 5) + (mt << 4);
    const unsigned short* srow = &S[(m0 + n) * 88 + (kq << 3)];
    short8 a0 = *(const short8*)(srow);
    short8 a1 = *(const short8*)(srow + 32);
    f32x4 c0 = {0.0f, 0.0f, 0.0f, 0.0f}, c1 = {0.0f, 0.0f, 0.0f, 0.0f};
    c0 = __builtin_amdgcn_mfma_f32_16x16x32_bf16(a0, B0a, c0, 0, 0, 0);
    c0 = __builtin_amdgcn_mfma_f32_16x16x32_bf16(a1, B0b, c0, 0, 0, 0);
    c1 = __builtin_amdgcn_mfma_f32_16x16x32_bf16(a0, B1a, c1, 0, 0, 0);
    c1 = __builtin_amdgcn_mfma_f32_16x16x32_bf16(a1, B1b, c1, 0, 0, 0);
    #pragma unroll
    for (int r = 0; r < 4; ++r) {
      float v0 = c0[r] + b0;
      v0 = 0.5f * v0 * (1.0f + erff(v0 * 0.70710678118654752f));
      float v1 = c1[r] + b1;
      v1 = 0.5f * v1 * (1.0f + erff(v1 * 0.70710678118654752f));
      float s = v0 * g0 + v1 * g1;
      s += __shfl_xor(s, 1);
      s += __shfl_xor(s, 2);
      s += __shfl_xor(s, 4);
      s += __shfl_xor(s, 8);
      if (n == 0) outp[m0 + (kq << 2) + r] = s + ob2;
    }
  }
}

extern "C" void kernel_launch(void* const* d_in, const int* in_sizes, int n_in,
                              void* d_out, int out_size, void* d_ws, size_t ws_size,
                              hipStream_t stream) {
  const float* x       = (const float*)d_in[0];
  const float* in_w    = (const float*)d_in[1];
  const float* in_b    = (const float*)d_in[2];
  const float* spec_wr = (const float*)d_in[3];
  const float* spec_wi = (const float*)d_in[4];
  const float* pw_w    = (const float*)d_in[5];
  const float* pw_b    = (const float*)d_in[6];
  const float* o1_w    = (const float*)d_in[7];
  const float* o1_b    = (const float*)d_in[8];
  const float* o2_w    = (const float*)d_in[9];
  const float* o2_b    = (const float*)d_in[10];
  float* ws = (float*)d_ws;
  unsigned short* hb = (unsigned short*)(ws + OFF_H);
  unsigned short* A2 = (unsigned short*)(ws + OFF_A2);
  float* Y      = ws + OFF_YA;
  float* Xf     = ws + OFF_XF;
  float* costab = ws + OFF_TAB;
  unsigned short* o1wbf = (unsigned short*)(ws + OFF_O1W);
  unsigned short* trig = (unsigned short*)(ws + OFF_TRIG);
  unsigned short* wt   = (unsigned short*)(ws + OFF_WT);
  unsigned short* trigT = (unsigned short*)(ws + OFF_TRIGT);
  float* out = (float*)d_out;

  k_init<<<73, 256, 0, stream>>>(ws, pw_w, o1_w);
  k_in<<<32768, 256, 0, stream>>>(x, in_w, in_b, hb);
  k_f1<<<2048, 256, 0, stream>>>(hb, trigT, Y);        // layer 0's F1 only
  for (int l = 0; l < NLAYER; ++l) {
    k_f2<<<512, 256, 0, stream>>>(Y, costab, Xf);
    k_spec<<<512, 256, 0, stream>>>(Xf, spec_wr + (long)l * 1048576,
                                    spec_wi + (long)l * 1048576, costab, A2);
    k_pw<<<2048, 512, 0, stream>>>(hb, A2, wt + l * 4096, trig, trigT,
                                   pw_b + l * 64, Y, (l < NLAYER - 1) ? 1 : 0);
  }
  k_out<<<4096, 256, 0, stream>>>(hb, o1wbf, o1_b, o2_w, o2_b, out);
}